// Round 14
// baseline (167.779 us; speedup 1.0000x reference)
//
#include <hip/hip_runtime.h>
#include <hip/hip_bf16.h>
#include <math.h>

#define B_   2
#define S_   2048
#define H_   16
#define DH_  64
#define D_   1024
#define OUT_ 1024
#define M_   (B_ * S_)   // 4096

typedef __attribute__((ext_vector_type(8))) short bf16x8;
typedef __attribute__((ext_vector_type(4))) float f32x4;
typedef __attribute__((ext_vector_type(4))) short short4v;

#define MFMA(a, b, c) __builtin_amdgcn_mfma_f32_16x16x32_bf16((a), (b), (c), 0, 0, 0)

__device__ __forceinline__ void gl_lds16(const void* g, void* l) {
    __builtin_amdgcn_global_load_lds(
        (const __attribute__((address_space(1))) unsigned int*)g,
        (__attribute__((address_space(3))) unsigned int*)l, 16, 0, 0);
}

__device__ __forceinline__ void split2(float x, unsigned short& h, unsigned short& l) {
    unsigned u = __float_as_uint(x);
    h = (unsigned short)(u >> 16);
    float lo = x - __uint_as_float(u & 0xFFFF0000u);
    l = (unsigned short)(__float_as_uint(lo) >> 16);
}

__device__ __forceinline__ unsigned short bf16_rne(float x) {
    return __builtin_bit_cast(unsigned short, __float2bfloat16(x));
}

__device__ __forceinline__ float fast_exp2(float x) {
#if __has_builtin(__builtin_amdgcn_exp2f)
    return __builtin_amdgcn_exp2f(x);
#else
    return exp2f(x);
#endif
}

// ---------------------------------------------------------------------------
// per-batch prefix sum of mask
// ---------------------------------------------------------------------------
__global__ __launch_bounds__(256)
void scan_mask(const float* __restrict__ mask, int* __restrict__ cpos,
               int* __restrict__ opos, int* __restrict__ nv)
{
    __shared__ int cnt[256];
    const int b = blockIdx.x, tid = threadIdx.x;
    const int base = b * 2048 + tid * 8;
    int mloc = 0, c = 0;
    #pragma unroll
    for (int i = 0; i < 8; ++i) {
        const int v = (mask[base + i] != 0.f) ? 1 : 0;
        mloc |= v << i;
        c += v;
    }
    cnt[tid] = c;
    __syncthreads();
    for (int off = 1; off < 256; off <<= 1) {
        const int v = cnt[tid];
        const int add = (tid >= off) ? cnt[tid - off] : 0;
        __syncthreads();
        cnt[tid] = v + add;
        __syncthreads();
    }
    int excl = cnt[tid] - c;
    #pragma unroll
    for (int i = 0; i < 8; ++i) {
        cpos[base + i] = excl;
        if ((mloc >> i) & 1) {
            opos[b * 2048 + excl] = tid * 8 + i;
            ++excl;
        }
    }
    if (tid == 255) nv[b] = cnt[255];
}

// ---------------------------------------------------------------------------
__global__ __launch_bounds__(256)
void split_x_c(const float* __restrict__ X, const float* __restrict__ mask,
               const int* __restrict__ cpos,
               unsigned short* __restrict__ Xh, unsigned short* __restrict__ Xl)
{
    const int row = blockIdx.x;            // 0..4095
    const int b = row >> 11, s = row & 2047;
    if (mask[(size_t)b * 2048 + s] == 0.f) return;
    const int cr = b * 2048 + cpos[b * 2048 + s];
    const int c4 = threadIdx.x * 4;
    const float4 v = *(const float4*)&X[(size_t)row * D_ + c4];
    unsigned short h[4], l[4];
    split2(v.x, h[0], l[0]); split2(v.y, h[1], l[1]);
    split2(v.z, h[2], l[2]); split2(v.w, h[3], l[3]);
    *(short4v*)&Xh[(size_t)cr * D_ + c4] =
        (short4v){(short)h[0],(short)h[1],(short)h[2],(short)h[3]};
    *(short4v*)&Xl[(size_t)cr * D_ + c4] =
        (short4v){(short)l[0],(short)l[1],(short)l[2],(short)l[3]};
}

// ---------------------------------------------------------------------------
__global__ __launch_bounds__(256)
void fill_out(float* __restrict__ out, const float* __restrict__ bo)
{
    const int i = blockIdx.x * 256 + threadIdx.x;   // float4 index
    ((float4*)out)[i] = ((const float4*)bo)[i & 255];
}

// ---------------------------------------------------------------------------
__global__ __launch_bounds__(256)
void tconv_w(const float* __restrict__ W, unsigned short* __restrict__ Th,
             unsigned short* __restrict__ Tl, int K, int N)
{
    __shared__ float T[64][65];
    const int tid = threadIdx.x;
    const int k0 = blockIdx.x * 64, n0 = blockIdx.y * 64;
    #pragma unroll
    for (int p = 0; p < 4; ++p) {
        const int f = p * 256 + tid;
        const int r = f >> 4, c4 = (f & 15) << 2;
        const float4 v = *(const float4*)&W[(size_t)(k0 + r) * N + n0 + c4];
        T[r][c4] = v.x; T[r][c4 + 1] = v.y; T[r][c4 + 2] = v.z; T[r][c4 + 3] = v.w;
    }
    __syncthreads();
    #pragma unroll
    for (int p = 0; p < 4; ++p) {
        const int f = p * 256 + tid;
        const int r = f >> 4, c4 = (f & 15) << 2;
        unsigned short h[4], l[4];
        #pragma unroll
        for (int i = 0; i < 4; ++i) split2(T[c4 + i][r], h[i], l[i]);
        *(short4v*)&Th[(size_t)(n0 + r) * K + k0 + c4] =
            (short4v){(short)h[0],(short)h[1],(short)h[2],(short)h[3]};
        *(short4v*)&Tl[(size_t)(n0 + r) * K + k0 + c4] =
            (short4v){(short)l[0],(short)l[1],(short)l[2],(short)l[3]};
    }
}

__global__ __launch_bounds__(256)
void tconv_qkv(const float* __restrict__ W0, const float* __restrict__ W1,
               const float* __restrict__ W2, unsigned short* __restrict__ Th,
               unsigned short* __restrict__ Tl)
{
    __shared__ float T[64][65];
    const int z = blockIdx.z;
    const float* W = (z == 0) ? W0 : (z == 1) ? W1 : W2;
    unsigned short* th = Th + ((size_t)z << 20);
    unsigned short* tl = Tl + ((size_t)z << 20);
    const int tid = threadIdx.x;
    const int k0 = blockIdx.x * 64, n0 = blockIdx.y * 64;
    #pragma unroll
    for (int p = 0; p < 4; ++p) {
        const int f = p * 256 + tid;
        const int r = f >> 4, c4 = (f & 15) << 2;
        const float4 v = *(const float4*)&W[(size_t)(k0 + r) * D_ + n0 + c4];
        T[r][c4] = v.x; T[r][c4 + 1] = v.y; T[r][c4 + 2] = v.z; T[r][c4 + 3] = v.w;
    }
    __syncthreads();
    #pragma unroll
    for (int p = 0; p < 4; ++p) {
        const int f = p * 256 + tid;
        const int r = f >> 4, c4 = (f & 15) << 2;
        unsigned short h[4], l[4];
        #pragma unroll
        for (int i = 0; i < 4; ++i) split2(T[c4 + i][r], h[i], l[i]);
        *(short4v*)&th[(size_t)(n0 + r) * D_ + k0 + c4] =
            (short4v){(short)h[0],(short)h[1],(short)h[2],(short)h[3]};
        *(short4v*)&tl[(size_t)(n0 + r) * D_ + k0 + c4] =
            (short4v){(short)l[0],(short)l[1],(short)l[2],(short)l[3]};
    }
}

// ---------------------------------------------------------------------------
// QKV GEMM, BM=128 BN=64, 4 waves, wave tile 64x32 (acc 4x2).
// 2-PHASE: BK=32, double-buffered LDS (48KB -> 3 blocks/CU). Per iteration:
// issue next tile's global_load_lds FIRST, compute current, one barrier
// (its vmcnt(0) lands after a full compute phase, not right after issue).
// Q cols: 3-term split. K/V cols: 2-term. Bit-identical K-order to round 13.
// ---------------------------------------------------------------------------
__global__ __launch_bounds__(256, 3)
void gemm_qkv(const unsigned short* __restrict__ Ah, const unsigned short* __restrict__ Al,
              const unsigned short* __restrict__ Bh, const unsigned short* __restrict__ Bl,
              const float* __restrict__ bq, const float* __restrict__ bk,
              const float* __restrict__ bv,
              unsigned short* __restrict__ Oqh, unsigned short* __restrict__ Oql,
              unsigned short* __restrict__ Okh, unsigned short* __restrict__ Ovt,
              const int* __restrict__ nv)
{
    const int n0 = blockIdx.x * 64, m0 = blockIdx.y * 128;
    const int bb = m0 >> 11;
    const int nvb = nv[bb];
    if ((m0 & 2047) >= nvb) return;

    __shared__ unsigned short As_h[2][128 * 32], As_l[2][128 * 32];
    __shared__ unsigned short Bs_h[2][64 * 32],  Bs_l[2][64 * 32];

    const int tid = threadIdx.x;
    const int lane = tid & 63, w = tid >> 6;
    const int wm = w >> 1, wn = w & 1;          // 2x2 wave grid, 64x32 each
    const int l15 = lane & 15, l4 = lane >> 4;
    const int srow4 = lane >> 2, sch = lane & 3;
    const int idx = n0 >> 10;                   // 0=Q 1=K 2=V

    f32x4 acc[4][2];
    #pragma unroll
    for (int i = 0; i < 4; ++i)
        #pragma unroll
        for (int j = 0; j < 2; ++j) acc[i][j] = (f32x4){0.f, 0.f, 0.f, 0.f};

#define QKV_STAGE(KT, SEL)                                                      \
    do {                                                                        \
        _Pragma("unroll")                                                       \
        for (int t = 0; t < 2; ++t) {           /* A: wave covers 32 rows */    \
            const int ar = w * 32 + t * 16 + srow4;                             \
            const int kc = sch ^ (ar & 3);                                      \
            const size_t g = (size_t)(m0 + ar) * D_ + (KT) + kc * 8;            \
            gl_lds16(&Ah[g], &As_h[SEL][(w * 32 + t * 16) * 32]);               \
            if (idx == 0)                                                       \
                gl_lds16(&Al[g], &As_l[SEL][(w * 32 + t * 16) * 32]);           \
        }                                                                       \
        {                                        /* B: wave covers 16 rows */   \
            const int br = w * 16 + srow4;                                      \
            const int kc = sch ^ (br & 3);                                      \
            const size_t g = (size_t)(n0 + br) * D_ + (KT) + kc * 8;            \
            gl_lds16(&Bh[g], &Bs_h[SEL][(w * 16) * 32]);                        \
            gl_lds16(&Bl[g], &Bs_l[SEL][(w * 16) * 32]);                        \
        }                                                                       \
    } while (0)

    QKV_STAGE(0, 0);
    __syncthreads();

    int cur = 0;
    for (int kt = 0; kt < D_; kt += 32, cur ^= 1) {
        if (kt + 32 < D_) QKV_STAGE(kt + 32, cur ^ 1);

        bf16x8 ah[4], bh2[2], bl2[2];
        #pragma unroll
        for (int i = 0; i < 4; ++i) {
            const int row = wm * 64 + i * 16 + l15;
            ah[i] = *(const bf16x8*)&As_h[cur][row * 32 + ((l4 ^ (row & 3)) << 3)];
        }
        #pragma unroll
        for (int j = 0; j < 2; ++j) {
            const int row = wn * 32 + j * 16 + l15;
            const int off = row * 32 + ((l4 ^ (row & 3)) << 3);
            bh2[j] = *(const bf16x8*)&Bs_h[cur][off];
            bl2[j] = *(const bf16x8*)&Bs_l[cur][off];
        }
        #pragma unroll
        for (int i = 0; i < 4; ++i)
            #pragma unroll
            for (int j = 0; j < 2; ++j) {
                acc[i][j] = MFMA(ah[i], bh2[j], acc[i][j]);
                acc[i][j] = MFMA(ah[i], bl2[j], acc[i][j]);
            }
        if (idx == 0) {   // Q: 3rd term with A-lo
            #pragma unroll
            for (int i = 0; i < 4; ++i) {
                const int row = wm * 64 + i * 16 + l15;
                const bf16x8 al = *(const bf16x8*)
                    &As_l[cur][row * 32 + ((l4 ^ (row & 3)) << 3)];
                #pragma unroll
                for (int j = 0; j < 2; ++j)
                    acc[i][j] = MFMA(al, bh2[j], acc[i][j]);
            }
        }

        __syncthreads();   // drains next-tile prefetch + this tile's LDS reads
    }
#undef QKV_STAGE

    const float* bp = (idx == 0) ? bq : (idx == 1) ? bk : bv;
    #pragma unroll
    for (int i = 0; i < 4; ++i) {
        const int m = m0 + wm * 64 + i * 16 + l4 * 4;
        const int jm = m & 2047;
        #pragma unroll
        for (int j = 0; j < 2; ++j) {
            const int nG = n0 + wn * 32 + j * 16 + l15;
            const int c = nG & 1023;
            const float bvv = bp[c];
            const int hh = c >> 6, dd = c & 63;
            if (idx == 0) {
                const size_t base = ((size_t)(bb * H_ + hh) * S_ + jm) * 64 + dd;
                #pragma unroll
                for (int r = 0; r < 4; ++r)
                    if (jm + r < nvb) {
                        unsigned short vh, vl;
                        split2(acc[i][j][r] + bvv, vh, vl);
                        Oqh[base + (size_t)r * 64] = vh;
                        Oql[base + (size_t)r * 64] = vl;
                    }
            } else if (idx == 1) {
                const size_t base = ((size_t)(bb * H_ + hh) * S_ + jm) * 64 + dd;
                #pragma unroll
                for (int r = 0; r < 4; ++r)
                    if (jm + r < nvb)
                        Okh[base + (size_t)r * 64] = bf16_rne(acc[i][j][r] + bvv);
            } else {
                unsigned short pv[4];
                #pragma unroll
                for (int r = 0; r < 4; ++r) pv[r] = bf16_rne(acc[i][j][r] + bvv);
                const size_t vb = ((size_t)(bb * H_ + hh) * 64 + dd) * (size_t)S_ + jm;
                if (jm + 3 < nvb) {
                    *(short4v*)&Ovt[vb] =
                        (short4v){(short)pv[0],(short)pv[1],(short)pv[2],(short)pv[3]};
                } else {
                    #pragma unroll
                    for (int r = 0; r < 4; ++r)
                        if (jm + r < nvb) Ovt[vb + r] = pv[r];
                }
            }
        }
    }
}

// ---------------------------------------------------------------------------
// Output GEMM, 64x64 tile, 4 waves, wave 32x32, 3-term, 2-PHASE BK=32
// double-buffered (32KB LDS -> 4 blocks/CU). Scatter via opos.
// ---------------------------------------------------------------------------
__global__ __launch_bounds__(256, 4)
void gemm_out64(const unsigned short* __restrict__ Ah, const unsigned short* __restrict__ Al,
                const unsigned short* __restrict__ Bh, const unsigned short* __restrict__ Bl,
                const float* __restrict__ bias, float* __restrict__ Cf,
                const int* __restrict__ nv, const int* __restrict__ opos)
{
    const int n0 = blockIdx.x * 64, m0 = blockIdx.y * 64;
    const int bb = m0 >> 11;
    const int nvb = nv[bb];
    if ((m0 & 2047) >= nvb) return;

    __shared__ unsigned short As_h[2][64 * 32], As_l[2][64 * 32];
    __shared__ unsigned short Bs_h[2][64 * 32], Bs_l[2][64 * 32];

    const int tid = threadIdx.x;
    const int lane = tid & 63, w = tid >> 6;
    const int wm = w >> 1, wn = w & 1;                // 2x2 wave grid, 32x32 each
    const int l15 = lane & 15, l4 = lane >> 4;
    const int srow4 = lane >> 2, sch = lane & 3;

    f32x4 acc[2][2];
    #pragma unroll
    for (int i = 0; i < 2; ++i)
        #pragma unroll
        for (int j = 0; j < 2; ++j) acc[i][j] = (f32x4){0.f, 0.f, 0.f, 0.f};

#define OUT_STAGE(KT, SEL)                                                      \
    do {                                                                        \
        const int r1 = w * 16 + srow4;                                          \
        const int kc = sch ^ (r1 & 3);                                          \
        const size_t ga = (size_t)(m0 + r1) * D_ + (KT) + kc * 8;               \
        gl_lds16(&Ah[ga], &As_h[SEL][(w * 16) * 32]);                           \
        gl_lds16(&Al[ga], &As_l[SEL][(w * 16) * 32]);                           \
        const size_t gb = (size_t)(n0 + r1) * D_ + (KT) + kc * 8;               \
        gl_lds16(&Bh[gb], &Bs_h[SEL][(w * 16) * 32]);                           \
        gl_lds16(&Bl[gb], &Bs_l[SEL][(w * 16) * 32]);                           \
    } while (0)

    OUT_STAGE(0, 0);
    __syncthreads();

    int cur = 0;
    for (int kt = 0; kt < D_; kt += 32, cur ^= 1) {
        if (kt + 32 < D_) OUT_STAGE(kt + 32, cur ^ 1);

        bf16x8 ah[2], al[2], bh2[2], bl2[2];
        #pragma unroll
        for (int i = 0; i < 2; ++i) {
            const int row = wm * 32 + i * 16 + l15;
            const int off = row * 32 + ((l4 ^ (row & 3)) << 3);
            ah[i] = *(const bf16x8*)&As_h[cur][off];
            al[i] = *(const bf16x8*)&As_l[cur][off];
        }
        #pragma unroll
        for (int j = 0; j < 2; ++j) {
            const int row = wn * 32 + j * 16 + l15;
            const int off = row * 32 + ((l4 ^ (row & 3)) << 3);
            bh2[j] = *(const bf16x8*)&Bs_h[cur][off];
            bl2[j] = *(const bf16x8*)&Bs_l[cur][off];
        }
        #pragma unroll
        for (int i = 0; i < 2; ++i)
            #pragma unroll
            for (int j = 0; j < 2; ++j) {
                acc[i][j] = MFMA(ah[i], bh2[j], acc[i][j]);
                acc[i][j] = MFMA(ah[i], bl2[j], acc[i][j]);
                acc[i][j] = MFMA(al[i], bh2[j], acc[i][j]);
            }

        __syncthreads();
    }
#undef OUT_STAGE

    const int* op = opos + bb * 2048;
    #pragma unroll
    for (int i = 0; i < 2; ++i) {
        const int m = m0 + wm * 32 + i * 16 + l4 * 4;
        #pragma unroll
        for (int j = 0; j < 2; ++j) {
            const int n = n0 + wn * 32 + j * 16 + l15;
            const float bvv = bias[n];
            #pragma unroll
            for (int r = 0; r < 4; ++r) {
                const int jr = (m & 2047) + r;
                if (jr < nvb)
                    Cf[((size_t)bb * 2048 + op[jr]) * OUT_ + n] = acc[i][j][r] + bvv;
            }
        }
    }
}

// ---------------------------------------------------------------------------
// Flash attention on COMPACTED q/k. 8 waves x 16 q-rows, 2-phase dbuf.
// ---------------------------------------------------------------------------
__global__ __launch_bounds__(512, 4)
void attn_mfma(const unsigned short* __restrict__ Qh, const unsigned short* __restrict__ Ql,
               const unsigned short* __restrict__ Kh, const unsigned short* __restrict__ Vt,
               const int* __restrict__ nv,
               unsigned short* __restrict__ Mh, unsigned short* __restrict__ Ml)
{
    const int bh = blockIdx.x, b = bh >> 4;
    const int nvb = nv[b];
    const int q0 = blockIdx.y * 128;
    if (q0 >= nvb) return;

    __shared__ unsigned short Ks[2][64 * 64];
    __shared__ unsigned short Vts[2][64 * 64];
    __shared__ unsigned short Psb[128 * 72];

    const float SC2  = 0.125f * 1.4426950408889634f;
    const float THR2 = 11.5415603f;
    const float MINIT = -1e5f;
    const float NEGB  = -1e30f;

    const int tid = threadIdx.x;
    const int lane = tid & 63, w = tid >> 6;
    const int l15 = lane & 15, l4 = lane >> 4;
    const int qw = q0 + w * 16;

    const int srow = w * 8 + (lane >> 3);
    const int skc  = (lane & 7) ^ (srow & 7);

    bf16x8 qh[2], ql[2];
    {
        const int qr = min(qw + l15, nvb - 1);
        const size_t qbase = ((size_t)bh * S_ + qr) * 64;
        #pragma unroll
        for (int kk = 0; kk < 2; ++kk) {
            qh[kk] = *(const bf16x8*)&Qh[qbase + kk * 32 + l4 * 8];
            ql[kk] = *(const bf16x8*)&Ql[qbase + kk * 32 + l4 * 8];
        }
    }

    float m2[4], lp[4];
    f32x4 O[4];
    #pragma unroll
    for (int r = 0; r < 4; ++r) { m2[r] = MINIT; lp[r] = 0.f; }
    #pragma unroll
    for (int df = 0; df < 4; ++df) O[df] = (f32x4){0.f, 0.f, 0.f, 0.f};

    const int NT = (nvb + 63) >> 6;

#define STAGE(KT, SEL)                                                          \
    do {                                                                        \
        gl_lds16(&Kh[((size_t)bh * S_ + (KT) + srow) * 64 + skc * 8],           \
                 &Ks[SEL][(w * 8) * 64]);                                       \
        gl_lds16(&Vt[((size_t)bh * 64 + srow) * (size_t)S_ + (KT) + skc * 8],   \
                 &Vts[SEL][(w * 8) * 64]);                                      \
    } while (0)

    STAGE(0, 0);
    __syncthreads();

    int cur = 0;
    for (int ti = 0; ti < NT; ++ti, cur ^= 1) {
        const int kt = ti * 64;
        if (ti + 1 < NT) STAGE((ti + 1) * 64, cur ^ 1);

        f32x4 s[4];
        #pragma unroll
        for (int nf = 0; nf < 4; ++nf) s[nf] = (f32x4){0.f, 0.f, 0.f, 0.f};
        #pragma unroll
        for (int nf = 0; nf < 4; ++nf) {
            const int krow = nf * 16 + l15;
            #pragma unroll
            for (int kk = 0; kk < 2; ++kk) {
                const int off = krow * 64 + (((kk * 4 + l4) ^ (krow & 7)) << 3);
                const bf16x8 kh8 = *(const bf16x8*)&Ks[cur][off];
                s[nf] = MFMA(qh[kk], kh8, s[nf]);
                s[nf] = MFMA(ql[kk], kh8, s[nf]);
            }
        }

        float addk[4];
        #pragma unroll
        for (int nf = 0; nf < 4; ++nf)
            addk[nf] = (kt + nf * 16 + l15 < nvb) ? 0.f : NEGB;

        float lm[4];
        bool need = false;
        #pragma unroll
        for (int r = 0; r < 4; ++r) {
            float v0 = fmaf(s[0][r], SC2, addk[0]);
            float v1 = fmaf(s[1][r], SC2, addk[1]);
            float v2 = fmaf(s[2][r], SC2, addk[2]);
            float v3 = fmaf(s[3][r], SC2, addk[3]);
            s[0][r] = v0; s[1][r] = v1; s[2][r] = v2; s[3][r] = v3;
            const float rm = fmaxf(fmaxf(v0, v1), fmaxf(v2, v3));
            lm[r] = rm;
            need |= (rm > m2[r] + THR2);
        }

        if (__any(need)) {
            #pragma unroll
            for (int r = 0; r < 4; ++r) {
                float rm = lm[r];
                rm = fmaxf(rm, __shfl_xor(rm, 1));
                rm = fmaxf(rm, __shfl_xor(rm, 2));
                rm = fmaxf(rm, __shfl_xor(rm, 4));
                rm = fmaxf(rm, __shfl_xor(rm, 8));
                const float mnew = fmaxf(m2[r], rm);
                const float sc = fast_exp2(m2[r] - mnew);
                lp[r] *= sc;
                m2[r] = mnew;
                #pragma unroll
                for (int df = 0; df < 4; ++df) O[df][r] *= sc;
            }
        }

        #pragma unroll
        for (int r = 0; r < 4; ++r) {
            const float mm = m2[r];
            const int qq = w * 16 + l4 * 4 + r;
            const int qbase = qq * 72;
            const int qswz = qq & 7;
            float rs = 0.f;
            #pragma unroll
            for (int nf = 0; nf < 4; ++nf) {
                const float pv = fast_exp2(s[nf][r] - mm);
                rs += pv;
                const int key = nf * 16 + l15;
                Psb[qbase + (((key >> 3) ^ qswz) << 3) + (key & 7)] = bf16_rne(pv);
            }
            lp[r] += rs;
        }

        #pragma unroll
        for (int kk = 0; kk < 2; ++kk) {
            const int qq = w * 16 + l15;
            const bf16x8 ph = *(const bf16x8*)
                &Psb[qq * 72 + ((((kk * 4) + l4) ^ (qq & 7)) << 3)];
            #pragma unroll
            for (int df = 0; df < 4; ++df) {
                const int vrow = df * 16 + l15;
                const int off = vrow * 64 + (((kk * 4 + l4) ^ (vrow & 7)) << 3);
                const bf16x8 vb = *(const bf16x8*)&Vts[cur][off];
                O[df] = MFMA(ph, vb, O[df]);
            }
        }

        __syncthreads();
    }
#undef STAGE

    #pragma unroll
    for (int r = 0; r < 4; ++r) {
        float t = lp[r];
        t += __shfl_xor(t, 1);
        t += __shfl_xor(t, 2);
        t += __shfl_xor(t, 4);
        t += __shfl_xor(t, 8);
        const int j = qw + l4 * 4 + r;
        if (j < nvb) {
            const float inv = (t > 0.f) ? 1.f / t : 0.f;
            const size_t base = ((size_t)b * S_ + j) * D_ + (bh & 15) * DH_;
            #pragma unroll
            for (int df = 0; df < 4; ++df) {
                unsigned short vh, vl;
                split2(O[df][r] * inv, vh, vl);
                Mh[base + df * 16 + l15] = vh;
                Ml[base + df * 16 + l15] = vl;
            }
        }
    }
}

// ---------------------------------------------------------------------------
extern "C" void kernel_launch(void* const* d_in, const int* in_sizes, int n_in,
                              void* d_out, int out_size, void* d_ws, size_t ws_size,
                              hipStream_t stream)
{
    const float* x    = (const float*)d_in[0];
    const float* mask = (const float*)d_in[1];
    const float* Wq   = (const float*)d_in[2];
    const float* bq   = (const float*)d_in[3];
    const float* Wk   = (const float*)d_in[4];
    const float* bk   = (const float*)d_in[5];
    const float* Wv   = (const float*)d_in[6];
    const float* bv   = (const float*)d_in[7];
    const float* Wo   = (const float*)d_in[8];
    const float* bo   = (const float*)d_in[9];
    float* out = (float*)d_out;

    char* ws = (char*)d_ws;
    unsigned short* xh = (unsigned short*)(ws);                      // 8MB (later mh)
    unsigned short* xl = (unsigned short*)(ws + ((size_t) 8 << 20)); // 8MB (later ml)
    unsigned short* qh = (unsigned short*)(ws + ((size_t)16 << 20));
    unsigned short* qll= (unsigned short*)(ws + ((size_t)24 << 20));
    unsigned short* kh = (unsigned short*)(ws + ((size_t)32 << 20));
    unsigned short* vt = (unsigned short*)(ws + ((size_t)40 << 20)); // V^T [bh][d][s]
    unsigned short* wc_h = (unsigned short*)(ws + ((size_t)48 << 20)); // 6MB
    unsigned short* wc_l = (unsigned short*)(ws + ((size_t)54 << 20)); // 6MB
    unsigned short* wo_h = wc_h;            // reuse after QKV GEMM
    unsigned short* wo_l = (unsigned short*)(ws + ((size_t)50 << 20));
    unsigned short* mh = xh;                // x dead after QKV GEMM
    unsigned short* ml = xl;
    int* cpos = (int*)(ws + ((size_t)60 << 20));          // 16KB
    int* opos = (int*)(ws + ((size_t)60 << 20) + 16384);  // 16KB
    int* nv   = (int*)(ws + ((size_t)60 << 20) + 32768);  // 8B

    const dim3 blk(256);
    scan_mask<<<dim3(B_), blk, 0, stream>>>(mask, cpos, opos, nv);
    split_x_c<<<dim3(M_), blk, 0, stream>>>(x, mask, cpos, xh, xl);
    tconv_qkv<<<dim3(16, 16, 3), blk, 0, stream>>>(Wq, Wk, Wv, wc_h, wc_l);

    // grid = (n-blocks, m-blocks): XCD = n%8 -> B-slices L2-resident
    gemm_qkv<<<dim3(3 * D_ / 64, M_ / 128), blk, 0, stream>>>(
        xh, xl, wc_h, wc_l, bq, bk, bv, qh, qll, kh, vt, nv);

    tconv_w<<<dim3(16, 16), blk, 0, stream>>>(Wo, wo_h, wo_l, D_, OUT_);

    attn_mfma<<<dim3(B_ * H_, S_ / 128), dim3(512), 0, stream>>>(
        qh, qll, kh, vt, nv, mh, ml);

    fill_out<<<dim3(M_ * OUT_ / 4 / 256), blk, 0, stream>>>(out, bo);

    gemm_out64<<<dim3(OUT_ / 64, M_ / 64), blk, 0, stream>>>(
        mh, ml, wo_h, wo_l, bo, out, nv, opos);
}

// Round 15
// 146.898 us; speedup vs baseline: 1.1421x; 1.1421x over previous
//
#include <hip/hip_runtime.h>
#include <hip/hip_bf16.h>
#include <math.h>

#define B_   2
#define S_   2048
#define H_   16
#define DH_  64
#define D_   1024
#define OUT_ 1024
#define M_   (B_ * S_)   // 4096

typedef __attribute__((ext_vector_type(8))) short bf16x8;
typedef __attribute__((ext_vector_type(4))) float f32x4;
typedef __attribute__((ext_vector_type(4))) short short4v;

#define MFMA(a, b, c) __builtin_amdgcn_mfma_f32_16x16x32_bf16((a), (b), (c), 0, 0, 0)

__device__ __forceinline__ void gl_lds16(const void* g, void* l) {
    __builtin_amdgcn_global_load_lds(
        (const __attribute__((address_space(1))) unsigned int*)g,
        (__attribute__((address_space(3))) unsigned int*)l, 16, 0, 0);
}

__device__ __forceinline__ void split2(float x, unsigned short& h, unsigned short& l) {
    unsigned u = __float_as_uint(x);
    h = (unsigned short)(u >> 16);
    float lo = x - __uint_as_float(u & 0xFFFF0000u);
    l = (unsigned short)(__float_as_uint(lo) >> 16);
}

__device__ __forceinline__ unsigned short bf16_rne(float x) {
    return __builtin_bit_cast(unsigned short, __float2bfloat16(x));
}

__device__ __forceinline__ float fast_exp2(float x) {
#if __has_builtin(__builtin_amdgcn_exp2f)
    return __builtin_amdgcn_exp2f(x);
#else
    return exp2f(x);
#endif
}

// ---------------------------------------------------------------------------
// per-batch prefix sum of mask
// ---------------------------------------------------------------------------
__global__ __launch_bounds__(256)
void scan_mask(const float* __restrict__ mask, int* __restrict__ cpos,
               int* __restrict__ opos, int* __restrict__ nv)
{
    __shared__ int cnt[256];
    const int b = blockIdx.x, tid = threadIdx.x;
    const int base = b * 2048 + tid * 8;
    int mloc = 0, c = 0;
    #pragma unroll
    for (int i = 0; i < 8; ++i) {
        const int v = (mask[base + i] != 0.f) ? 1 : 0;
        mloc |= v << i;
        c += v;
    }
    cnt[tid] = c;
    __syncthreads();
    for (int off = 1; off < 256; off <<= 1) {
        const int v = cnt[tid];
        const int add = (tid >= off) ? cnt[tid - off] : 0;
        __syncthreads();
        cnt[tid] = v + add;
        __syncthreads();
    }
    int excl = cnt[tid] - c;
    #pragma unroll
    for (int i = 0; i < 8; ++i) {
        cpos[base + i] = excl;
        if ((mloc >> i) & 1) {
            opos[b * 2048 + excl] = tid * 8 + i;
            ++excl;
        }
    }
    if (tid == 255) nv[b] = cnt[255];
}

// ---------------------------------------------------------------------------
__global__ __launch_bounds__(256)
void split_x_c(const float* __restrict__ X, const float* __restrict__ mask,
               const int* __restrict__ cpos,
               unsigned short* __restrict__ Xh, unsigned short* __restrict__ Xl)
{
    const int row = blockIdx.x;            // 0..4095
    const int b = row >> 11, s = row & 2047;
    if (mask[(size_t)b * 2048 + s] == 0.f) return;
    const int cr = b * 2048 + cpos[b * 2048 + s];
    const int c4 = threadIdx.x * 4;
    const float4 v = *(const float4*)&X[(size_t)row * D_ + c4];
    unsigned short h[4], l[4];
    split2(v.x, h[0], l[0]); split2(v.y, h[1], l[1]);
    split2(v.z, h[2], l[2]); split2(v.w, h[3], l[3]);
    *(short4v*)&Xh[(size_t)cr * D_ + c4] =
        (short4v){(short)h[0],(short)h[1],(short)h[2],(short)h[3]};
    *(short4v*)&Xl[(size_t)cr * D_ + c4] =
        (short4v){(short)l[0],(short)l[1],(short)l[2],(short)l[3]};
}

// ---------------------------------------------------------------------------
__global__ __launch_bounds__(256)
void fill_out(float* __restrict__ out, const float* __restrict__ bo)
{
    const int i = blockIdx.x * 256 + threadIdx.x;   // float4 index
    ((float4*)out)[i] = ((const float4*)bo)[i & 255];
}

// ---------------------------------------------------------------------------
__global__ __launch_bounds__(256)
void tconv_w(const float* __restrict__ W, unsigned short* __restrict__ Th,
             unsigned short* __restrict__ Tl, int K, int N)
{
    __shared__ float T[64][65];
    const int tid = threadIdx.x;
    const int k0 = blockIdx.x * 64, n0 = blockIdx.y * 64;
    #pragma unroll
    for (int p = 0; p < 4; ++p) {
        const int f = p * 256 + tid;
        const int r = f >> 4, c4 = (f & 15) << 2;
        const float4 v = *(const float4*)&W[(size_t)(k0 + r) * N + n0 + c4];
        T[r][c4] = v.x; T[r][c4 + 1] = v.y; T[r][c4 + 2] = v.z; T[r][c4 + 3] = v.w;
    }
    __syncthreads();
    #pragma unroll
    for (int p = 0; p < 4; ++p) {
        const int f = p * 256 + tid;
        const int r = f >> 4, c4 = (f & 15) << 2;
        unsigned short h[4], l[4];
        #pragma unroll
        for (int i = 0; i < 4; ++i) split2(T[c4 + i][r], h[i], l[i]);
        *(short4v*)&Th[(size_t)(n0 + r) * K + k0 + c4] =
            (short4v){(short)h[0],(short)h[1],(short)h[2],(short)h[3]};
        *(short4v*)&Tl[(size_t)(n0 + r) * K + k0 + c4] =
            (short4v){(short)l[0],(short)l[1],(short)l[2],(short)l[3]};
    }
}

__global__ __launch_bounds__(256)
void tconv_qkv(const float* __restrict__ W0, const float* __restrict__ W1,
               const float* __restrict__ W2, unsigned short* __restrict__ Th,
               unsigned short* __restrict__ Tl)
{
    __shared__ float T[64][65];
    const int z = blockIdx.z;
    const float* W = (z == 0) ? W0 : (z == 1) ? W1 : W2;
    unsigned short* th = Th + ((size_t)z << 20);
    unsigned short* tl = Tl + ((size_t)z << 20);
    const int tid = threadIdx.x;
    const int k0 = blockIdx.x * 64, n0 = blockIdx.y * 64;
    #pragma unroll
    for (int p = 0; p < 4; ++p) {
        const int f = p * 256 + tid;
        const int r = f >> 4, c4 = (f & 15) << 2;
        const float4 v = *(const float4*)&W[(size_t)(k0 + r) * D_ + n0 + c4];
        T[r][c4] = v.x; T[r][c4 + 1] = v.y; T[r][c4 + 2] = v.z; T[r][c4 + 3] = v.w;
    }
    __syncthreads();
    #pragma unroll
    for (int p = 0; p < 4; ++p) {
        const int f = p * 256 + tid;
        const int r = f >> 4, c4 = (f & 15) << 2;
        unsigned short h[4], l[4];
        #pragma unroll
        for (int i = 0; i < 4; ++i) split2(T[c4 + i][r], h[i], l[i]);
        *(short4v*)&th[(size_t)(n0 + r) * D_ + k0 + c4] =
            (short4v){(short)h[0],(short)h[1],(short)h[2],(short)h[3]};
        *(short4v*)&tl[(size_t)(n0 + r) * D_ + k0 + c4] =
            (short4v){(short)l[0],(short)l[1],(short)l[2],(short)l[3]};
    }
}

// ---------------------------------------------------------------------------
// QKV GEMM, BM=128 BN=64, 4 waves, wave tile 64x32 (acc 4x2). BK=64, 1-phase
// (round-13 structure: best measured, 0 bank conflicts). Grid (n, m): XCD=n%8
// keeps each B-slice L2-resident. Q cols 3-term; K/V cols 2-term.
// ---------------------------------------------------------------------------
__global__ __launch_bounds__(256, 3)
void gemm_qkv(const unsigned short* __restrict__ Ah, const unsigned short* __restrict__ Al,
              const unsigned short* __restrict__ Bh, const unsigned short* __restrict__ Bl,
              const float* __restrict__ bq, const float* __restrict__ bk,
              const float* __restrict__ bv,
              unsigned short* __restrict__ Oqh, unsigned short* __restrict__ Oql,
              unsigned short* __restrict__ Okh, unsigned short* __restrict__ Ovt,
              const int* __restrict__ nv)
{
    const int n0 = blockIdx.x * 64, m0 = blockIdx.y * 128;
    const int bb = m0 >> 11;
    const int nvb = nv[bb];
    if ((m0 & 2047) >= nvb) return;

    __shared__ unsigned short As_h[128 * 64], As_l[128 * 64];
    __shared__ unsigned short Bs_h[64 * 64],  Bs_l[64 * 64];

    const int tid = threadIdx.x;
    const int lane = tid & 63, w = tid >> 6;
    const int wm = w >> 1, wn = w & 1;          // 2x2 wave grid, 64x32 each
    const int l15 = lane & 15, l4 = lane >> 4;
    const int lr = lane >> 3, lc = lane & 7;
    const int idx = n0 >> 10;                   // 0=Q 1=K 2=V

    f32x4 acc[4][2];
    #pragma unroll
    for (int i = 0; i < 4; ++i)
        #pragma unroll
        for (int j = 0; j < 2; ++j) acc[i][j] = (f32x4){0.f, 0.f, 0.f, 0.f};

    for (int kt = 0; kt < D_; kt += 64) {
        __syncthreads();
        #pragma unroll
        for (int t = 0; t < 4; ++t) {           // A: 128 rows, wave covers 32
            const int row = w * 32 + t * 8 + lr;
            const int kc = lc ^ (row & 7);
            const size_t g = (size_t)(m0 + row) * D_ + kt + kc * 8;
            gl_lds16(&Ah[g], &As_h[(w * 32 + t * 8) * 64]);
            if (idx == 0)                        // A-lo only needed for Q
                gl_lds16(&Al[g], &As_l[(w * 32 + t * 8) * 64]);
        }
        #pragma unroll
        for (int t = 0; t < 2; ++t) {           // B: 64 rows, wave covers 16
            const int row = w * 16 + t * 8 + lr;
            const int kc = lc ^ (row & 7);
            const size_t g = (size_t)(n0 + row) * D_ + kt + kc * 8;
            gl_lds16(&Bh[g], &Bs_h[(w * 16 + t * 8) * 64]);
            gl_lds16(&Bl[g], &Bs_l[(w * 16 + t * 8) * 64]);
        }
        __syncthreads();

        #pragma unroll
        for (int kk = 0; kk < 2; ++kk) {
            bf16x8 ah[4], bh2[2], bl2[2];
            #pragma unroll
            for (int i = 0; i < 4; ++i) {
                const int row = wm * 64 + i * 16 + l15;
                const int off = row * 64 + (((kk * 4 + l4) ^ (row & 7)) << 3);
                ah[i] = *(const bf16x8*)&As_h[off];
            }
            #pragma unroll
            for (int j = 0; j < 2; ++j) {
                const int row = wn * 32 + j * 16 + l15;
                const int off = row * 64 + (((kk * 4 + l4) ^ (row & 7)) << 3);
                bh2[j] = *(const bf16x8*)&Bs_h[off];
                bl2[j] = *(const bf16x8*)&Bs_l[off];
            }
            #pragma unroll
            for (int i = 0; i < 4; ++i)
                #pragma unroll
                for (int j = 0; j < 2; ++j) {
                    acc[i][j] = MFMA(ah[i], bh2[j], acc[i][j]);
                    acc[i][j] = MFMA(ah[i], bl2[j], acc[i][j]);
                }
            if (idx == 0) {   // Q: 3rd term with A-lo
                #pragma unroll
                for (int i = 0; i < 4; ++i) {
                    const int row = wm * 64 + i * 16 + l15;
                    const int off = row * 64 + (((kk * 4 + l4) ^ (row & 7)) << 3);
                    const bf16x8 al = *(const bf16x8*)&As_l[off];
                    #pragma unroll
                    for (int j = 0; j < 2; ++j)
                        acc[i][j] = MFMA(al, bh2[j], acc[i][j]);
                }
            }
        }
    }

    const float* bp = (idx == 0) ? bq : (idx == 1) ? bk : bv;
    #pragma unroll
    for (int i = 0; i < 4; ++i) {
        const int m = m0 + wm * 64 + i * 16 + l4 * 4;
        const int jm = m & 2047;
        #pragma unroll
        for (int j = 0; j < 2; ++j) {
            const int nG = n0 + wn * 32 + j * 16 + l15;
            const int c = nG & 1023;
            const float bvv = bp[c];
            const int hh = c >> 6, dd = c & 63;
            if (idx == 0) {
                const size_t base = ((size_t)(bb * H_ + hh) * S_ + jm) * 64 + dd;
                #pragma unroll
                for (int r = 0; r < 4; ++r)
                    if (jm + r < nvb) {
                        unsigned short vh, vl;
                        split2(acc[i][j][r] + bvv, vh, vl);
                        Oqh[base + (size_t)r * 64] = vh;
                        Oql[base + (size_t)r * 64] = vl;
                    }
            } else if (idx == 1) {
                const size_t base = ((size_t)(bb * H_ + hh) * S_ + jm) * 64 + dd;
                #pragma unroll
                for (int r = 0; r < 4; ++r)
                    if (jm + r < nvb)
                        Okh[base + (size_t)r * 64] = bf16_rne(acc[i][j][r] + bvv);
            } else {
                unsigned short pv[4];
                #pragma unroll
                for (int r = 0; r < 4; ++r) pv[r] = bf16_rne(acc[i][j][r] + bvv);
                const size_t vb = ((size_t)(bb * H_ + hh) * 64 + dd) * (size_t)S_ + jm;
                if (jm + 3 < nvb) {
                    *(short4v*)&Ovt[vb] =
                        (short4v){(short)pv[0],(short)pv[1],(short)pv[2],(short)pv[3]};
                } else {
                    #pragma unroll
                    for (int r = 0; r < 4; ++r)
                        if (jm + r < nvb) Ovt[vb + r] = pv[r];
                }
            }
        }
    }
}

// ---------------------------------------------------------------------------
// Output GEMM, 64x64 tile, 4 waves, wave 32x32, 3-term, BK=64 1-phase
// (round-13 structure). Scatter via opos.
// ---------------------------------------------------------------------------
__global__ __launch_bounds__(256, 4)
void gemm_out64(const unsigned short* __restrict__ Ah, const unsigned short* __restrict__ Al,
                const unsigned short* __restrict__ Bh, const unsigned short* __restrict__ Bl,
                const float* __restrict__ bias, float* __restrict__ Cf,
                const int* __restrict__ nv, const int* __restrict__ opos)
{
    const int n0 = blockIdx.x * 64, m0 = blockIdx.y * 64;
    const int bb = m0 >> 11;
    const int nvb = nv[bb];
    if ((m0 & 2047) >= nvb) return;

    __shared__ unsigned short As_h[64 * 64], As_l[64 * 64];
    __shared__ unsigned short Bs_h[64 * 64], Bs_l[64 * 64];

    const int tid = threadIdx.x;
    const int lane = tid & 63, w = tid >> 6;
    const int wm = w >> 1, wn = w & 1;                // 2x2 wave grid, 32x32 each
    const int l15 = lane & 15, l4 = lane >> 4;
    const int lr = lane >> 3, lc = lane & 7;

    f32x4 acc[2][2];
    #pragma unroll
    for (int i = 0; i < 2; ++i)
        #pragma unroll
        for (int j = 0; j < 2; ++j) acc[i][j] = (f32x4){0.f, 0.f, 0.f, 0.f};

    for (int kt = 0; kt < D_; kt += 64) {
        __syncthreads();
        #pragma unroll
        for (int t = 0; t < 2; ++t) {
            const int row = w * 16 + t * 8 + lr;
            const int kc = lc ^ (row & 7);
            const size_t ga = (size_t)(m0 + row) * D_ + kt + kc * 8;
            gl_lds16(&Ah[ga], &As_h[(w * 16 + t * 8) * 64]);
            gl_lds16(&Al[ga], &As_l[(w * 16 + t * 8) * 64]);
            const size_t gb = (size_t)(n0 + row) * D_ + kt + kc * 8;
            gl_lds16(&Bh[gb], &Bs_h[(w * 16 + t * 8) * 64]);
            gl_lds16(&Bl[gb], &Bs_l[(w * 16 + t * 8) * 64]);
        }
        __syncthreads();

        #pragma unroll
        for (int kk = 0; kk < 2; ++kk) {
            bf16x8 ah[2], al[2], bh2[2], bl2[2];
            #pragma unroll
            for (int i = 0; i < 2; ++i) {
                const int row = wm * 32 + i * 16 + l15;
                const int off = row * 64 + (((kk * 4 + l4) ^ (row & 7)) << 3);
                ah[i] = *(const bf16x8*)&As_h[off];
                al[i] = *(const bf16x8*)&As_l[off];
            }
            #pragma unroll
            for (int j = 0; j < 2; ++j) {
                const int row = wn * 32 + j * 16 + l15;
                const int off = row * 64 + (((kk * 4 + l4) ^ (row & 7)) << 3);
                bh2[j] = *(const bf16x8*)&Bs_h[off];
                bl2[j] = *(const bf16x8*)&Bs_l[off];
            }
            #pragma unroll
            for (int i = 0; i < 2; ++i)
                #pragma unroll
                for (int j = 0; j < 2; ++j) {
                    acc[i][j] = MFMA(ah[i], bh2[j], acc[i][j]);
                    acc[i][j] = MFMA(ah[i], bl2[j], acc[i][j]);
                    acc[i][j] = MFMA(al[i], bh2[j], acc[i][j]);
                }
        }
    }

    const int* op = opos + bb * 2048;
    #pragma unroll
    for (int i = 0; i < 2; ++i) {
        const int m = m0 + wm * 32 + i * 16 + l4 * 4;
        #pragma unroll
        for (int j = 0; j < 2; ++j) {
            const int n = n0 + wn * 32 + j * 16 + l15;
            const float bvv = bias[n];
            #pragma unroll
            for (int r = 0; r < 4; ++r) {
                const int jr = (m & 2047) + r;
                if (jr < nvb)
                    Cf[((size_t)bb * 2048 + op[jr]) * OUT_ + n] = acc[i][j][r] + bvv;
            }
        }
    }
}

// ---------------------------------------------------------------------------
// Flash attention on COMPACTED q/k. QBLK=64: 4 waves x 16 q-rows (256 thr),
// doubling active blocks to ~512 (2 blocks/CU, 4 waves/SIMD; LDS 41KB allows
// 3/CU). Per-wave code identical to the QBLK=128 version. 2-phase dbuf.
// ---------------------------------------------------------------------------
__global__ __launch_bounds__(256, 3)
void attn_mfma(const unsigned short* __restrict__ Qh, const unsigned short* __restrict__ Ql,
               const unsigned short* __restrict__ Kh, const unsigned short* __restrict__ Vt,
               const int* __restrict__ nv,
               unsigned short* __restrict__ Mh, unsigned short* __restrict__ Ml)
{
    const int bh = blockIdx.x, b = bh >> 4;
    const int nvb = nv[b];
    const int q0 = blockIdx.y * 64;
    if (q0 >= nvb) return;

    __shared__ unsigned short Ks[2][64 * 64];
    __shared__ unsigned short Vts[2][64 * 64];
    __shared__ unsigned short Psb[64 * 72];

    const float SC2  = 0.125f * 1.4426950408889634f;
    const float THR2 = 11.5415603f;
    const float MINIT = -1e5f;
    const float NEGB  = -1e30f;

    const int tid = threadIdx.x;
    const int lane = tid & 63, w = tid >> 6;     // w = 0..3
    const int l15 = lane & 15, l4 = lane >> 4;
    const int qw = q0 + w * 16;

    const int sr8 = lane >> 3, sc7 = lane & 7;

    bf16x8 qh[2], ql[2];
    {
        const int qr = min(qw + l15, nvb - 1);
        const size_t qbase = ((size_t)bh * S_ + qr) * 64;
        #pragma unroll
        for (int kk = 0; kk < 2; ++kk) {
            qh[kk] = *(const bf16x8*)&Qh[qbase + kk * 32 + l4 * 8];
            ql[kk] = *(const bf16x8*)&Ql[qbase + kk * 32 + l4 * 8];
        }
    }

    float m2[4], lp[4];
    f32x4 O[4];
    #pragma unroll
    for (int r = 0; r < 4; ++r) { m2[r] = MINIT; lp[r] = 0.f; }
    #pragma unroll
    for (int df = 0; df < 4; ++df) O[df] = (f32x4){0.f, 0.f, 0.f, 0.f};

    const int NT = (nvb + 63) >> 6;

#define STAGE(KT, SEL)                                                          \
    do {                                                                        \
        _Pragma("unroll")                                                       \
        for (int t = 0; t < 2; ++t) {                                           \
            const int row = w * 16 + t * 8 + sr8;                               \
            const int kc = sc7 ^ (row & 7);                                     \
            gl_lds16(&Kh[((size_t)bh * S_ + (KT) + row) * 64 + kc * 8],         \
                     &Ks[SEL][(w * 16 + t * 8) * 64]);                          \
            gl_lds16(&Vt[((size_t)bh * 64 + row) * (size_t)S_ + (KT) + kc * 8], \
                     &Vts[SEL][(w * 16 + t * 8) * 64]);                         \
        }                                                                       \
    } while (0)

    STAGE(0, 0);
    __syncthreads();

    int cur = 0;
    for (int ti = 0; ti < NT; ++ti, cur ^= 1) {
        const int kt = ti * 64;
        if (ti + 1 < NT) STAGE((ti + 1) * 64, cur ^ 1);

        f32x4 s[4];
        #pragma unroll
        for (int nf = 0; nf < 4; ++nf) s[nf] = (f32x4){0.f, 0.f, 0.f, 0.f};
        #pragma unroll
        for (int nf = 0; nf < 4; ++nf) {
            const int krow = nf * 16 + l15;
            #pragma unroll
            for (int kk = 0; kk < 2; ++kk) {
                const int off = krow * 64 + (((kk * 4 + l4) ^ (krow & 7)) << 3);
                const bf16x8 kh8 = *(const bf16x8*)&Ks[cur][off];
                s[nf] = MFMA(qh[kk], kh8, s[nf]);
                s[nf] = MFMA(ql[kk], kh8, s[nf]);
            }
        }

        float addk[4];
        #pragma unroll
        for (int nf = 0; nf < 4; ++nf)
            addk[nf] = (kt + nf * 16 + l15 < nvb) ? 0.f : NEGB;

        float lm[4];
        bool need = false;
        #pragma unroll
        for (int r = 0; r < 4; ++r) {
            float v0 = fmaf(s[0][r], SC2, addk[0]);
            float v1 = fmaf(s[1][r], SC2, addk[1]);
            float v2 = fmaf(s[2][r], SC2, addk[2]);
            float v3 = fmaf(s[3][r], SC2, addk[3]);
            s[0][r] = v0; s[1][r] = v1; s[2][r] = v2; s[3][r] = v3;
            const float rm = fmaxf(fmaxf(v0, v1), fmaxf(v2, v3));
            lm[r] = rm;
            need |= (rm > m2[r] + THR2);
        }

        if (__any(need)) {
            #pragma unroll
            for (int r = 0; r < 4; ++r) {
                float rm = lm[r];
                rm = fmaxf(rm, __shfl_xor(rm, 1));
                rm = fmaxf(rm, __shfl_xor(rm, 2));
                rm = fmaxf(rm, __shfl_xor(rm, 4));
                rm = fmaxf(rm, __shfl_xor(rm, 8));
                const float mnew = fmaxf(m2[r], rm);
                const float sc = fast_exp2(m2[r] - mnew);
                lp[r] *= sc;
                m2[r] = mnew;
                #pragma unroll
                for (int df = 0; df < 4; ++df) O[df][r] *= sc;
            }
        }

        #pragma unroll
        for (int r = 0; r < 4; ++r) {
            const float mm = m2[r];
            const int qq = w * 16 + l4 * 4 + r;
            const int qbase = qq * 72;
            const int qswz = qq & 7;
            float rs = 0.f;
            #pragma unroll
            for (int nf = 0; nf < 4; ++nf) {
                const float pv = fast_exp2(s[nf][r] - mm);
                rs += pv;
                const int key = nf * 16 + l15;
                Psb[qbase + (((key >> 3) ^ qswz) << 3) + (key & 7)] = bf16_rne(pv);
            }
            lp[r] += rs;
        }

        #pragma unroll
        for (int kk = 0; kk < 2; ++kk) {
            const int qq = w * 16 + l15;
            const bf16x8 ph = *(const bf16x8*)
                &Psb[qq * 72 + ((((kk * 4) + l4) ^ (qq & 7)) << 3)];
            #pragma unroll
            for (int df = 0; df < 4; ++df) {
                const int vrow = df * 16 + l15;
                const int off = vrow * 64 + (((kk * 4 + l4) ^ (vrow & 7)) << 3);
                const bf16x8 vb = *(const bf16x8*)&Vts[cur][off];
                O[df] = MFMA(ph, vb, O[df]);
            }
        }

        __syncthreads();
    }
#undef STAGE

    #pragma unroll
    for (int r = 0; r < 4; ++r) {
        float t = lp[r];
        t += __shfl_xor(t, 1);
        t += __shfl_xor(t, 2);
        t += __shfl_xor(t, 4);
        t += __shfl_xor(t, 8);
        const int j = qw + l4 * 4 + r;
        if (j < nvb) {
            const float inv = (t > 0.f) ? 1.f / t : 0.f;
            const size_t base = ((size_t)b * S_ + j) * D_ + (bh & 15) * DH_;
            #pragma unroll
            for (int df = 0; df < 4; ++df) {
                unsigned short vh, vl;
                split2(O[df][r] * inv, vh, vl);
                Mh[base + df * 16 + l15] = vh;
                Ml[base + df * 16 + l15] = vl;
            }
        }
    }
}

// ---------------------------------------------------------------------------
extern "C" void kernel_launch(void* const* d_in, const int* in_sizes, int n_in,
                              void* d_out, int out_size, void* d_ws, size_t ws_size,
                              hipStream_t stream)
{
    const float* x    = (const float*)d_in[0];
    const float* mask = (const float*)d_in[1];
    const float* Wq   = (const float*)d_in[2];
    const float* bq   = (const float*)d_in[3];
    const float* Wk   = (const float*)d_in[4];
    const float* bk   = (const float*)d_in[5];
    const float* Wv   = (const float*)d_in[6];
    const float* bv   = (const float*)d_in[7];
    const float* Wo   = (const float*)d_in[8];
    const float* bo   = (const float*)d_in[9];
    float* out = (float*)d_out;

    char* ws = (char*)d_ws;
    unsigned short* xh = (unsigned short*)(ws);                      // 8MB (later mh)
    unsigned short* xl = (unsigned short*)(ws + ((size_t) 8 << 20)); // 8MB (later ml)
    unsigned short* qh = (unsigned short*)(ws + ((size_t)16 << 20));
    unsigned short* qll= (unsigned short*)(ws + ((size_t)24 << 20));
    unsigned short* kh = (unsigned short*)(ws + ((size_t)32 << 20));
    unsigned short* vt = (unsigned short*)(ws + ((size_t)40 << 20)); // V^T [bh][d][s]
    unsigned short* wc_h = (unsigned short*)(ws + ((size_t)48 << 20)); // 6MB
    unsigned short* wc_l = (unsigned short*)(ws + ((size_t)54 << 20)); // 6MB
    unsigned short* wo_h = wc_h;            // reuse after QKV GEMM
    unsigned short* wo_l = (unsigned short*)(ws + ((size_t)50 << 20));
    unsigned short* mh = xh;                // x dead after QKV GEMM
    unsigned short* ml = xl;
    int* cpos = (int*)(ws + ((size_t)60 << 20));          // 16KB
    int* opos = (int*)(ws + ((size_t)60 << 20) + 16384);  // 16KB
    int* nv   = (int*)(ws + ((size_t)60 << 20) + 32768);  // 8B

    const dim3 blk(256);
    scan_mask<<<dim3(B_), blk, 0, stream>>>(mask, cpos, opos, nv);
    split_x_c<<<dim3(M_), blk, 0, stream>>>(x, mask, cpos, xh, xl);
    tconv_qkv<<<dim3(16, 16, 3), blk, 0, stream>>>(Wq, Wk, Wv, wc_h, wc_l);

    // grid = (n-blocks, m-blocks): XCD = n%8 -> B-slices L2-resident
    gemm_qkv<<<dim3(3 * D_ / 64, M_ / 128), blk, 0, stream>>>(
        xh, xl, wc_h, wc_l, bq, bk, bv, qh, qll, kh, vt, nv);

    tconv_w<<<dim3(16, 16), blk, 0, stream>>>(Wo, wo_h, wo_l, D_, OUT_);

    attn_mfma<<<dim3(B_ * H_, S_ / 64), blk, 0, stream>>>(
        qh, qll, kh, vt, nv, mh, ml);

    fill_out<<<dim3(M_ * OUT_ / 4 / 256), blk, 0, stream>>>(out, bo);

    gemm_out64<<<dim3(OUT_ / 64, M_ / 64), blk, 0, stream>>>(
        mh, ml, wo_h, wo_l, bo, out, nv, opos);
}

// Round 16
// 145.346 us; speedup vs baseline: 1.1543x; 1.0107x over previous
//
#include <hip/hip_runtime.h>
#include <hip/hip_bf16.h>
#include <math.h>

#define B_   2
#define S_   2048
#define H_   16
#define DH_  64
#define D_   1024
#define OUT_ 1024
#define M_   (B_ * S_)   // 4096

typedef __attribute__((ext_vector_type(8))) short bf16x8;
typedef __attribute__((ext_vector_type(4))) float f32x4;
typedef __attribute__((ext_vector_type(4))) short short4v;

#define MFMA(a, b, c) __builtin_amdgcn_mfma_f32_16x16x32_bf16((a), (b), (c), 0, 0, 0)

__device__ __forceinline__ void gl_lds16(const void* g, void* l) {
    __builtin_amdgcn_global_load_lds(
        (const __attribute__((address_space(1))) unsigned int*)g,
        (__attribute__((address_space(3))) unsigned int*)l, 16, 0, 0);
}

__device__ __forceinline__ void split2(float x, unsigned short& h, unsigned short& l) {
    unsigned u = __float_as_uint(x);
    h = (unsigned short)(u >> 16);
    float lo = x - __uint_as_float(u & 0xFFFF0000u);
    l = (unsigned short)(__float_as_uint(lo) >> 16);
}

__device__ __forceinline__ unsigned short bf16_rne(float x) {
    return __builtin_bit_cast(unsigned short, __float2bfloat16(x));
}

__device__ __forceinline__ float fast_exp2(float x) {
#if __has_builtin(__builtin_amdgcn_exp2f)
    return __builtin_amdgcn_exp2f(x);
#else
    return exp2f(x);
#endif
}

// ---------------------------------------------------------------------------
// per-batch prefix sum of mask
// ---------------------------------------------------------------------------
__global__ __launch_bounds__(256)
void scan_mask(const float* __restrict__ mask, int* __restrict__ cpos,
               int* __restrict__ opos, int* __restrict__ nv)
{
    __shared__ int cnt[256];
    const int b = blockIdx.x, tid = threadIdx.x;
    const int base = b * 2048 + tid * 8;
    int mloc = 0, c = 0;
    #pragma unroll
    for (int i = 0; i < 8; ++i) {
        const int v = (mask[base + i] != 0.f) ? 1 : 0;
        mloc |= v << i;
        c += v;
    }
    cnt[tid] = c;
    __syncthreads();
    for (int off = 1; off < 256; off <<= 1) {
        const int v = cnt[tid];
        const int add = (tid >= off) ? cnt[tid - off] : 0;
        __syncthreads();
        cnt[tid] = v + add;
        __syncthreads();
    }
    int excl = cnt[tid] - c;
    #pragma unroll
    for (int i = 0; i < 8; ++i) {
        cpos[base + i] = excl;
        if ((mloc >> i) & 1) {
            opos[b * 2048 + excl] = tid * 8 + i;
            ++excl;
        }
    }
    if (tid == 255) nv[b] = cnt[255];
}

// ---------------------------------------------------------------------------
__global__ __launch_bounds__(256)
void split_x_c(const float* __restrict__ X, const float* __restrict__ mask,
               const int* __restrict__ cpos,
               unsigned short* __restrict__ Xh, unsigned short* __restrict__ Xl)
{
    const int row = blockIdx.x;            // 0..4095
    const int b = row >> 11, s = row & 2047;
    if (mask[(size_t)b * 2048 + s] == 0.f) return;
    const int cr = b * 2048 + cpos[b * 2048 + s];
    const int c4 = threadIdx.x * 4;
    const float4 v = *(const float4*)&X[(size_t)row * D_ + c4];
    unsigned short h[4], l[4];
    split2(v.x, h[0], l[0]); split2(v.y, h[1], l[1]);
    split2(v.z, h[2], l[2]); split2(v.w, h[3], l[3]);
    *(short4v*)&Xh[(size_t)cr * D_ + c4] =
        (short4v){(short)h[0],(short)h[1],(short)h[2],(short)h[3]};
    *(short4v*)&Xl[(size_t)cr * D_ + c4] =
        (short4v){(short)l[0],(short)l[1],(short)l[2],(short)l[3]};
}

// ---------------------------------------------------------------------------
// out[row] = bias for MASKED rows only (their exact result). Valid rows are
// fully overwritten by gemm_out64's scatter, so skipping them is exact.
// ---------------------------------------------------------------------------
__global__ __launch_bounds__(256)
void fill_out(float* __restrict__ out, const float* __restrict__ bo,
              const float* __restrict__ mask)
{
    const int row = blockIdx.x;            // 0..4095
    const int b = row >> 11, s = row & 2047;
    if (mask[(size_t)b * 2048 + s] != 0.f) return;
    const int c4 = threadIdx.x * 4;
    *(float4*)&out[(size_t)row * OUT_ + c4] = *(const float4*)&bo[c4];
}

// ---------------------------------------------------------------------------
__global__ __launch_bounds__(256)
void tconv_w(const float* __restrict__ W, unsigned short* __restrict__ Th,
             unsigned short* __restrict__ Tl, int K, int N)
{
    __shared__ float T[64][65];
    const int tid = threadIdx.x;
    const int k0 = blockIdx.x * 64, n0 = blockIdx.y * 64;
    #pragma unroll
    for (int p = 0; p < 4; ++p) {
        const int f = p * 256 + tid;
        const int r = f >> 4, c4 = (f & 15) << 2;
        const float4 v = *(const float4*)&W[(size_t)(k0 + r) * N + n0 + c4];
        T[r][c4] = v.x; T[r][c4 + 1] = v.y; T[r][c4 + 2] = v.z; T[r][c4 + 3] = v.w;
    }
    __syncthreads();
    #pragma unroll
    for (int p = 0; p < 4; ++p) {
        const int f = p * 256 + tid;
        const int r = f >> 4, c4 = (f & 15) << 2;
        unsigned short h[4], l[4];
        #pragma unroll
        for (int i = 0; i < 4; ++i) split2(T[c4 + i][r], h[i], l[i]);
        *(short4v*)&Th[(size_t)(n0 + r) * K + k0 + c4] =
            (short4v){(short)h[0],(short)h[1],(short)h[2],(short)h[3]};
        *(short4v*)&Tl[(size_t)(n0 + r) * K + k0 + c4] =
            (short4v){(short)l[0],(short)l[1],(short)l[2],(short)l[3]};
    }
}

__global__ __launch_bounds__(256)
void tconv_qkv(const float* __restrict__ W0, const float* __restrict__ W1,
               const float* __restrict__ W2, unsigned short* __restrict__ Th,
               unsigned short* __restrict__ Tl)
{
    __shared__ float T[64][65];
    const int z = blockIdx.z;
    const float* W = (z == 0) ? W0 : (z == 1) ? W1 : W2;
    unsigned short* th = Th + ((size_t)z << 20);
    unsigned short* tl = Tl + ((size_t)z << 20);
    const int tid = threadIdx.x;
    const int k0 = blockIdx.x * 64, n0 = blockIdx.y * 64;
    #pragma unroll
    for (int p = 0; p < 4; ++p) {
        const int f = p * 256 + tid;
        const int r = f >> 4, c4 = (f & 15) << 2;
        const float4 v = *(const float4*)&W[(size_t)(k0 + r) * D_ + n0 + c4];
        T[r][c4] = v.x; T[r][c4 + 1] = v.y; T[r][c4 + 2] = v.z; T[r][c4 + 3] = v.w;
    }
    __syncthreads();
    #pragma unroll
    for (int p = 0; p < 4; ++p) {
        const int f = p * 256 + tid;
        const int r = f >> 4, c4 = (f & 15) << 2;
        unsigned short h[4], l[4];
        #pragma unroll
        for (int i = 0; i < 4; ++i) split2(T[c4 + i][r], h[i], l[i]);
        *(short4v*)&th[(size_t)(n0 + r) * D_ + k0 + c4] =
            (short4v){(short)h[0],(short)h[1],(short)h[2],(short)h[3]};
        *(short4v*)&tl[(size_t)(n0 + r) * D_ + k0 + c4] =
            (short4v){(short)l[0],(short)l[1],(short)l[2],(short)l[3]};
    }
}

// ---------------------------------------------------------------------------
// QKV GEMM, BM=128 BN=64, 4 waves, wave tile 64x32 (acc 4x2). BK=64, 1-phase
// (best measured structure, 0 bank conflicts). Grid (n, m): XCD=n%8 keeps
// each B-slice L2-resident. Q cols 3-term; K/V cols 2-term.
// ---------------------------------------------------------------------------
__global__ __launch_bounds__(256, 3)
void gemm_qkv(const unsigned short* __restrict__ Ah, const unsigned short* __restrict__ Al,
              const unsigned short* __restrict__ Bh, const unsigned short* __restrict__ Bl,
              const float* __restrict__ bq, const float* __restrict__ bk,
              const float* __restrict__ bv,
              unsigned short* __restrict__ Oqh, unsigned short* __restrict__ Oql,
              unsigned short* __restrict__ Okh, unsigned short* __restrict__ Ovt,
              const int* __restrict__ nv)
{
    const int n0 = blockIdx.x * 64, m0 = blockIdx.y * 128;
    const int bb = m0 >> 11;
    const int nvb = nv[bb];
    if ((m0 & 2047) >= nvb) return;

    __shared__ unsigned short As_h[128 * 64], As_l[128 * 64];
    __shared__ unsigned short Bs_h[64 * 64],  Bs_l[64 * 64];

    const int tid = threadIdx.x;
    const int lane = tid & 63, w = tid >> 6;
    const int wm = w >> 1, wn = w & 1;          // 2x2 wave grid, 64x32 each
    const int l15 = lane & 15, l4 = lane >> 4;
    const int lr = lane >> 3, lc = lane & 7;
    const int idx = n0 >> 10;                   // 0=Q 1=K 2=V

    f32x4 acc[4][2];
    #pragma unroll
    for (int i = 0; i < 4; ++i)
        #pragma unroll
        for (int j = 0; j < 2; ++j) acc[i][j] = (f32x4){0.f, 0.f, 0.f, 0.f};

    for (int kt = 0; kt < D_; kt += 64) {
        __syncthreads();
        #pragma unroll
        for (int t = 0; t < 4; ++t) {           // A: 128 rows, wave covers 32
            const int row = w * 32 + t * 8 + lr;
            const int kc = lc ^ (row & 7);
            const size_t g = (size_t)(m0 + row) * D_ + kt + kc * 8;
            gl_lds16(&Ah[g], &As_h[(w * 32 + t * 8) * 64]);
            if (idx == 0)                        // A-lo only needed for Q
                gl_lds16(&Al[g], &As_l[(w * 32 + t * 8) * 64]);
        }
        #pragma unroll
        for (int t = 0; t < 2; ++t) {           // B: 64 rows, wave covers 16
            const int row = w * 16 + t * 8 + lr;
            const int kc = lc ^ (row & 7);
            const size_t g = (size_t)(n0 + row) * D_ + kt + kc * 8;
            gl_lds16(&Bh[g], &Bs_h[(w * 16 + t * 8) * 64]);
            gl_lds16(&Bl[g], &Bs_l[(w * 16 + t * 8) * 64]);
        }
        __syncthreads();

        #pragma unroll
        for (int kk = 0; kk < 2; ++kk) {
            bf16x8 ah[4], bh2[2], bl2[2];
            #pragma unroll
            for (int i = 0; i < 4; ++i) {
                const int row = wm * 64 + i * 16 + l15;
                const int off = row * 64 + (((kk * 4 + l4) ^ (row & 7)) << 3);
                ah[i] = *(const bf16x8*)&As_h[off];
            }
            #pragma unroll
            for (int j = 0; j < 2; ++j) {
                const int row = wn * 32 + j * 16 + l15;
                const int off = row * 64 + (((kk * 4 + l4) ^ (row & 7)) << 3);
                bh2[j] = *(const bf16x8*)&Bs_h[off];
                bl2[j] = *(const bf16x8*)&Bs_l[off];
            }
            #pragma unroll
            for (int i = 0; i < 4; ++i)
                #pragma unroll
                for (int j = 0; j < 2; ++j) {
                    acc[i][j] = MFMA(ah[i], bh2[j], acc[i][j]);
                    acc[i][j] = MFMA(ah[i], bl2[j], acc[i][j]);
                }
            if (idx == 0) {   // Q: 3rd term with A-lo
                #pragma unroll
                for (int i = 0; i < 4; ++i) {
                    const int row = wm * 64 + i * 16 + l15;
                    const int off = row * 64 + (((kk * 4 + l4) ^ (row & 7)) << 3);
                    const bf16x8 al = *(const bf16x8*)&As_l[off];
                    #pragma unroll
                    for (int j = 0; j < 2; ++j)
                        acc[i][j] = MFMA(al, bh2[j], acc[i][j]);
                }
            }
        }
    }

    const float* bp = (idx == 0) ? bq : (idx == 1) ? bk : bv;
    #pragma unroll
    for (int i = 0; i < 4; ++i) {
        const int m = m0 + wm * 64 + i * 16 + l4 * 4;
        const int jm = m & 2047;
        #pragma unroll
        for (int j = 0; j < 2; ++j) {
            const int nG = n0 + wn * 32 + j * 16 + l15;
            const int c = nG & 1023;
            const float bvv = bp[c];
            const int hh = c >> 6, dd = c & 63;
            if (idx == 0) {
                const size_t base = ((size_t)(bb * H_ + hh) * S_ + jm) * 64 + dd;
                #pragma unroll
                for (int r = 0; r < 4; ++r)
                    if (jm + r < nvb) {
                        unsigned short vh, vl;
                        split2(acc[i][j][r] + bvv, vh, vl);
                        Oqh[base + (size_t)r * 64] = vh;
                        Oql[base + (size_t)r * 64] = vl;
                    }
            } else if (idx == 1) {
                const size_t base = ((size_t)(bb * H_ + hh) * S_ + jm) * 64 + dd;
                #pragma unroll
                for (int r = 0; r < 4; ++r)
                    if (jm + r < nvb)
                        Okh[base + (size_t)r * 64] = bf16_rne(acc[i][j][r] + bvv);
            } else {
                unsigned short pv[4];
                #pragma unroll
                for (int r = 0; r < 4; ++r) pv[r] = bf16_rne(acc[i][j][r] + bvv);
                const size_t vb = ((size_t)(bb * H_ + hh) * 64 + dd) * (size_t)S_ + jm;
                if (jm + 3 < nvb) {
                    *(short4v*)&Ovt[vb] =
                        (short4v){(short)pv[0],(short)pv[1],(short)pv[2],(short)pv[3]};
                } else {
                    #pragma unroll
                    for (int r = 0; r < 4; ++r)
                        if (jm + r < nvb) Ovt[vb + r] = pv[r];
                }
            }
        }
    }
}

// ---------------------------------------------------------------------------
// Output GEMM, 64x64 tile, 4 waves, wave 32x32, 3-term, BK=64 1-phase.
// Scatter via opos.
// ---------------------------------------------------------------------------
__global__ __launch_bounds__(256, 4)
void gemm_out64(const unsigned short* __restrict__ Ah, const unsigned short* __restrict__ Al,
                const unsigned short* __restrict__ Bh, const unsigned short* __restrict__ Bl,
                const float* __restrict__ bias, float* __restrict__ Cf,
                const int* __restrict__ nv, const int* __restrict__ opos)
{
    const int n0 = blockIdx.x * 64, m0 = blockIdx.y * 64;
    const int bb = m0 >> 11;
    const int nvb = nv[bb];
    if ((m0 & 2047) >= nvb) return;

    __shared__ unsigned short As_h[64 * 64], As_l[64 * 64];
    __shared__ unsigned short Bs_h[64 * 64], Bs_l[64 * 64];

    const int tid = threadIdx.x;
    const int lane = tid & 63, w = tid >> 6;
    const int wm = w >> 1, wn = w & 1;                // 2x2 wave grid, 32x32 each
    const int l15 = lane & 15, l4 = lane >> 4;
    const int lr = lane >> 3, lc = lane & 7;

    f32x4 acc[2][2];
    #pragma unroll
    for (int i = 0; i < 2; ++i)
        #pragma unroll
        for (int j = 0; j < 2; ++j) acc[i][j] = (f32x4){0.f, 0.f, 0.f, 0.f};

    for (int kt = 0; kt < D_; kt += 64) {
        __syncthreads();
        #pragma unroll
        for (int t = 0; t < 2; ++t) {
            const int row = w * 16 + t * 8 + lr;
            const int kc = lc ^ (row & 7);
            const size_t ga = (size_t)(m0 + row) * D_ + kt + kc * 8;
            gl_lds16(&Ah[ga], &As_h[(w * 16 + t * 8) * 64]);
            gl_lds16(&Al[ga], &As_l[(w * 16 + t * 8) * 64]);
            const size_t gb = (size_t)(n0 + row) * D_ + kt + kc * 8;
            gl_lds16(&Bh[gb], &Bs_h[(w * 16 + t * 8) * 64]);
            gl_lds16(&Bl[gb], &Bs_l[(w * 16 + t * 8) * 64]);
        }
        __syncthreads();

        #pragma unroll
        for (int kk = 0; kk < 2; ++kk) {
            bf16x8 ah[2], al[2], bh2[2], bl2[2];
            #pragma unroll
            for (int i = 0; i < 2; ++i) {
                const int row = wm * 32 + i * 16 + l15;
                const int off = row * 64 + (((kk * 4 + l4) ^ (row & 7)) << 3);
                ah[i] = *(const bf16x8*)&As_h[off];
                al[i] = *(const bf16x8*)&As_l[off];
            }
            #pragma unroll
            for (int j = 0; j < 2; ++j) {
                const int row = wn * 32 + j * 16 + l15;
                const int off = row * 64 + (((kk * 4 + l4) ^ (row & 7)) << 3);
                bh2[j] = *(const bf16x8*)&Bs_h[off];
                bl2[j] = *(const bf16x8*)&Bs_l[off];
            }
            #pragma unroll
            for (int i = 0; i < 2; ++i)
                #pragma unroll
                for (int j = 0; j < 2; ++j) {
                    acc[i][j] = MFMA(ah[i], bh2[j], acc[i][j]);
                    acc[i][j] = MFMA(ah[i], bl2[j], acc[i][j]);
                    acc[i][j] = MFMA(al[i], bh2[j], acc[i][j]);
                }
        }
    }

    const int* op = opos + bb * 2048;
    #pragma unroll
    for (int i = 0; i < 2; ++i) {
        const int m = m0 + wm * 32 + i * 16 + l4 * 4;
        #pragma unroll
        for (int j = 0; j < 2; ++j) {
            const int n = n0 + wn * 32 + j * 16 + l15;
            const float bvv = bias[n];
            #pragma unroll
            for (int r = 0; r < 4; ++r) {
                const int jr = (m & 2047) + r;
                if (jr < nvb)
                    Cf[((size_t)bb * 2048 + op[jr]) * OUT_ + n] = acc[i][j][r] + bvv;
            }
        }
    }
}

// ---------------------------------------------------------------------------
// Flash attention on COMPACTED q/k. QBLK=64: 4 waves x 16 q-rows (256 thr),
// ~512 active blocks (2/CU, 4 waves/SIMD). 2-phase dbuf staging.
// ---------------------------------------------------------------------------
__global__ __launch_bounds__(256, 3)
void attn_mfma(const unsigned short* __restrict__ Qh, const unsigned short* __restrict__ Ql,
               const unsigned short* __restrict__ Kh, const unsigned short* __restrict__ Vt,
               const int* __restrict__ nv,
               unsigned short* __restrict__ Mh, unsigned short* __restrict__ Ml)
{
    const int bh = blockIdx.x, b = bh >> 4;
    const int nvb = nv[b];
    const int q0 = blockIdx.y * 64;
    if (q0 >= nvb) return;

    __shared__ unsigned short Ks[2][64 * 64];
    __shared__ unsigned short Vts[2][64 * 64];
    __shared__ unsigned short Psb[64 * 72];

    const float SC2  = 0.125f * 1.4426950408889634f;
    const float THR2 = 11.5415603f;
    const float MINIT = -1e5f;
    const float NEGB  = -1e30f;

    const int tid = threadIdx.x;
    const int lane = tid & 63, w = tid >> 6;     // w = 0..3
    const int l15 = lane & 15, l4 = lane >> 4;
    const int qw = q0 + w * 16;

    const int sr8 = lane >> 3, sc7 = lane & 7;

    bf16x8 qh[2], ql[2];
    {
        const int qr = min(qw + l15, nvb - 1);
        const size_t qbase = ((size_t)bh * S_ + qr) * 64;
        #pragma unroll
        for (int kk = 0; kk < 2; ++kk) {
            qh[kk] = *(const bf16x8*)&Qh[qbase + kk * 32 + l4 * 8];
            ql[kk] = *(const bf16x8*)&Ql[qbase + kk * 32 + l4 * 8];
        }
    }

    float m2[4], lp[4];
    f32x4 O[4];
    #pragma unroll
    for (int r = 0; r < 4; ++r) { m2[r] = MINIT; lp[r] = 0.f; }
    #pragma unroll
    for (int df = 0; df < 4; ++df) O[df] = (f32x4){0.f, 0.f, 0.f, 0.f};

    const int NT = (nvb + 63) >> 6;

#define STAGE(KT, SEL)                                                          \
    do {                                                                        \
        _Pragma("unroll")                                                       \
        for (int t = 0; t < 2; ++t) {                                           \
            const int row = w * 16 + t * 8 + sr8;                               \
            const int kc = sc7 ^ (row & 7);                                     \
            gl_lds16(&Kh[((size_t)bh * S_ + (KT) + row) * 64 + kc * 8],         \
                     &Ks[SEL][(w * 16 + t * 8) * 64]);                          \
            gl_lds16(&Vt[((size_t)bh * 64 + row) * (size_t)S_ + (KT) + kc * 8], \
                     &Vts[SEL][(w * 16 + t * 8) * 64]);                         \
        }                                                                       \
    } while (0)

    STAGE(0, 0);
    __syncthreads();

    int cur = 0;
    for (int ti = 0; ti < NT; ++ti, cur ^= 1) {
        const int kt = ti * 64;
        if (ti + 1 < NT) STAGE((ti + 1) * 64, cur ^ 1);

        f32x4 s[4];
        #pragma unroll
        for (int nf = 0; nf < 4; ++nf) s[nf] = (f32x4){0.f, 0.f, 0.f, 0.f};
        #pragma unroll
        for (int nf = 0; nf < 4; ++nf) {
            const int krow = nf * 16 + l15;
            #pragma unroll
            for (int kk = 0; kk < 2; ++kk) {
                const int off = krow * 64 + (((kk * 4 + l4) ^ (krow & 7)) << 3);
                const bf16x8 kh8 = *(const bf16x8*)&Ks[cur][off];
                s[nf] = MFMA(qh[kk], kh8, s[nf]);
                s[nf] = MFMA(ql[kk], kh8, s[nf]);
            }
        }

        float addk[4];
        #pragma unroll
        for (int nf = 0; nf < 4; ++nf)
            addk[nf] = (kt + nf * 16 + l15 < nvb) ? 0.f : NEGB;

        float lm[4];
        bool need = false;
        #pragma unroll
        for (int r = 0; r < 4; ++r) {
            float v0 = fmaf(s[0][r], SC2, addk[0]);
            float v1 = fmaf(s[1][r], SC2, addk[1]);
            float v2 = fmaf(s[2][r], SC2, addk[2]);
            float v3 = fmaf(s[3][r], SC2, addk[3]);
            s[0][r] = v0; s[1][r] = v1; s[2][r] = v2; s[3][r] = v3;
            const float rm = fmaxf(fmaxf(v0, v1), fmaxf(v2, v3));
            lm[r] = rm;
            need |= (rm > m2[r] + THR2);
        }

        if (__any(need)) {
            #pragma unroll
            for (int r = 0; r < 4; ++r) {
                float rm = lm[r];
                rm = fmaxf(rm, __shfl_xor(rm, 1));
                rm = fmaxf(rm, __shfl_xor(rm, 2));
                rm = fmaxf(rm, __shfl_xor(rm, 4));
                rm = fmaxf(rm, __shfl_xor(rm, 8));
                const float mnew = fmaxf(m2[r], rm);
                const float sc = fast_exp2(m2[r] - mnew);
                lp[r] *= sc;
                m2[r] = mnew;
                #pragma unroll
                for (int df = 0; df < 4; ++df) O[df][r] *= sc;
            }
        }

        #pragma unroll
        for (int r = 0; r < 4; ++r) {
            const float mm = m2[r];
            const int qq = w * 16 + l4 * 4 + r;
            const int qbase = qq * 72;
            const int qswz = qq & 7;
            float rs = 0.f;
            #pragma unroll
            for (int nf = 0; nf < 4; ++nf) {
                const float pv = fast_exp2(s[nf][r] - mm);
                rs += pv;
                const int key = nf * 16 + l15;
                Psb[qbase + (((key >> 3) ^ qswz) << 3) + (key & 7)] = bf16_rne(pv);
            }
            lp[r] += rs;
        }

        #pragma unroll
        for (int kk = 0; kk < 2; ++kk) {
            const int qq = w * 16 + l15;
            const bf16x8 ph = *(const bf16x8*)
                &Psb[qq * 72 + ((((kk * 4) + l4) ^ (qq & 7)) << 3)];
            #pragma unroll
            for (int df = 0; df < 4; ++df) {
                const int vrow = df * 16 + l15;
                const int off = vrow * 64 + (((kk * 4 + l4) ^ (vrow & 7)) << 3);
                const bf16x8 vb = *(const bf16x8*)&Vts[cur][off];
                O[df] = MFMA(ph, vb, O[df]);
            }
        }

        __syncthreads();
    }
#undef STAGE

    #pragma unroll
    for (int r = 0; r < 4; ++r) {
        float t = lp[r];
        t += __shfl_xor(t, 1);
        t += __shfl_xor(t, 2);
        t += __shfl_xor(t, 4);
        t += __shfl_xor(t, 8);
        const int j = qw + l4 * 4 + r;
        if (j < nvb) {
            const float inv = (t > 0.f) ? 1.f / t : 0.f;
            const size_t base = ((size_t)b * S_ + j) * D_ + (bh & 15) * DH_;
            #pragma unroll
            for (int df = 0; df < 4; ++df) {
                unsigned short vh, vl;
                split2(O[df][r] * inv, vh, vl);
                Mh[base + df * 16 + l15] = vh;
                Ml[base + df * 16 + l15] = vl;
            }
        }
    }
}

// ---------------------------------------------------------------------------
extern "C" void kernel_launch(void* const* d_in, const int* in_sizes, int n_in,
                              void* d_out, int out_size, void* d_ws, size_t ws_size,
                              hipStream_t stream)
{
    const float* x    = (const float*)d_in[0];
    const float* mask = (const float*)d_in[1];
    const float* Wq   = (const float*)d_in[2];
    const float* bq   = (const float*)d_in[3];
    const float* Wk   = (const float*)d_in[4];
    const float* bk   = (const float*)d_in[5];
    const float* Wv   = (const float*)d_in[6];
    const float* bv   = (const float*)d_in[7];
    const float* Wo   = (const float*)d_in[8];
    const float* bo   = (const float*)d_in[9];
    float* out = (float*)d_out;

    char* ws = (char*)d_ws;
    unsigned short* xh = (unsigned short*)(ws);                      // 8MB (later mh)
    unsigned short* xl = (unsigned short*)(ws + ((size_t) 8 << 20)); // 8MB (later ml)
    unsigned short* qh = (unsigned short*)(ws + ((size_t)16 << 20));
    unsigned short* qll= (unsigned short*)(ws + ((size_t)24 << 20));
    unsigned short* kh = (unsigned short*)(ws + ((size_t)32 << 20));
    unsigned short* vt = (unsigned short*)(ws + ((size_t)40 << 20)); // V^T [bh][d][s]
    unsigned short* wc_h = (unsigned short*)(ws + ((size_t)48 << 20)); // 6MB
    unsigned short* wc_l = (unsigned short*)(ws + ((size_t)54 << 20)); // 6MB
    unsigned short* wo_h = wc_h;            // reuse after QKV GEMM
    unsigned short* wo_l = (unsigned short*)(ws + ((size_t)50 << 20));
    unsigned short* mh = xh;                // x dead after QKV GEMM
    unsigned short* ml = xl;
    int* cpos = (int*)(ws + ((size_t)60 << 20));          // 16KB
    int* opos = (int*)(ws + ((size_t)60 << 20) + 16384);  // 16KB
    int* nv   = (int*)(ws + ((size_t)60 << 20) + 32768);  // 8B

    const dim3 blk(256);
    scan_mask<<<dim3(B_), blk, 0, stream>>>(mask, cpos, opos, nv);
    split_x_c<<<dim3(M_), blk, 0, stream>>>(x, mask, cpos, xh, xl);
    tconv_qkv<<<dim3(16, 16, 3), blk, 0, stream>>>(Wq, Wk, Wv, wc_h, wc_l);

    // grid = (n-blocks, m-blocks): XCD = n%8 -> B-slices L2-resident
    gemm_qkv<<<dim3(3 * D_ / 64, M_ / 128), blk, 0, stream>>>(
        xh, xl, wc_h, wc_l, bq, bk, bv, qh, qll, kh, vt, nv);

    tconv_w<<<dim3(16, 16), blk, 0, stream>>>(Wo, wo_h, wo_l, D_, OUT_);

    attn_mfma<<<dim3(B_ * H_, S_ / 64), blk, 0, stream>>>(
        qh, qll, kh, vt, nv, mh, ml);

    fill_out<<<dim3(M_), blk, 0, stream>>>(out, bo, mask);

    gemm_out64<<<dim3(OUT_ / 64, M_ / 64), blk, 0, stream>>>(
        mh, ml, wo_h, wo_l, bo, out, nv, opos);
}

// Round 17
// 140.027 us; speedup vs baseline: 1.1982x; 1.0380x over previous
//
#include <hip/hip_runtime.h>
#include <hip/hip_bf16.h>
#include <math.h>

#define B_   2
#define S_   2048
#define H_   16
#define DH_  64
#define D_   1024
#define OUT_ 1024
#define M_   (B_ * S_)   // 4096

typedef __attribute__((ext_vector_type(8))) short bf16x8;
typedef __attribute__((ext_vector_type(4))) float f32x4;
typedef __attribute__((ext_vector_type(4))) short short4v;

#define MFMA(a, b, c) __builtin_amdgcn_mfma_f32_16x16x32_bf16((a), (b), (c), 0, 0, 0)

__device__ __forceinline__ void gl_lds16(const void* g, void* l) {
    __builtin_amdgcn_global_load_lds(
        (const __attribute__((address_space(1))) unsigned int*)g,
        (__attribute__((address_space(3))) unsigned int*)l, 16, 0, 0);
}

__device__ __forceinline__ void split2(float x, unsigned short& h, unsigned short& l) {
    unsigned u = __float_as_uint(x);
    h = (unsigned short)(u >> 16);
    float lo = x - __uint_as_float(u & 0xFFFF0000u);
    l = (unsigned short)(__float_as_uint(lo) >> 16);
}

__device__ __forceinline__ unsigned short bf16_rne(float x) {
    return __builtin_bit_cast(unsigned short, __float2bfloat16(x));
}

__device__ __forceinline__ float fast_exp2(float x) {
#if __has_builtin(__builtin_amdgcn_exp2f)
    return __builtin_amdgcn_exp2f(x);
#else
    return exp2f(x);
#endif
}

// ---------------------------------------------------------------------------
// per-batch prefix sum of mask
// ---------------------------------------------------------------------------
__global__ __launch_bounds__(256)
void scan_mask(const float* __restrict__ mask, int* __restrict__ cpos,
               int* __restrict__ opos, int* __restrict__ nv)
{
    __shared__ int cnt[256];
    const int b = blockIdx.x, tid = threadIdx.x;
    const int base = b * 2048 + tid * 8;
    int mloc = 0, c = 0;
    #pragma unroll
    for (int i = 0; i < 8; ++i) {
        const int v = (mask[base + i] != 0.f) ? 1 : 0;
        mloc |= v << i;
        c += v;
    }
    cnt[tid] = c;
    __syncthreads();
    for (int off = 1; off < 256; off <<= 1) {
        const int v = cnt[tid];
        const int add = (tid >= off) ? cnt[tid - off] : 0;
        __syncthreads();
        cnt[tid] = v + add;
        __syncthreads();
    }
    int excl = cnt[tid] - c;
    #pragma unroll
    for (int i = 0; i < 8; ++i) {
        cpos[base + i] = excl;
        if ((mloc >> i) & 1) {
            opos[b * 2048 + excl] = tid * 8 + i;
            ++excl;
        }
    }
    if (tid == 255) nv[b] = cnt[255];
}

// ---------------------------------------------------------------------------
// Valid rows: split+compact x. Masked rows: write out[row] = bias (exact
// final result; gemm_out64 only writes valid rows). Replaces fill_out.
// ---------------------------------------------------------------------------
__global__ __launch_bounds__(256)
void split_x_c(const float* __restrict__ X, const float* __restrict__ mask,
               const int* __restrict__ cpos,
               unsigned short* __restrict__ Xh, unsigned short* __restrict__ Xl,
               float* __restrict__ out, const float* __restrict__ bo)
{
    const int row = blockIdx.x;            // 0..4095
    const int b = row >> 11, s = row & 2047;
    const int c4 = threadIdx.x * 4;
    if (mask[(size_t)b * 2048 + s] == 0.f) {
        *(float4*)&out[(size_t)row * OUT_ + c4] = *(const float4*)&bo[c4];
        return;
    }
    const int cr = b * 2048 + cpos[b * 2048 + s];
    const float4 v = *(const float4*)&X[(size_t)row * D_ + c4];
    unsigned short h[4], l[4];
    split2(v.x, h[0], l[0]); split2(v.y, h[1], l[1]);
    split2(v.z, h[2], l[2]); split2(v.w, h[3], l[3]);
    *(short4v*)&Xh[(size_t)cr * D_ + c4] =
        (short4v){(short)h[0],(short)h[1],(short)h[2],(short)h[3]};
    *(short4v*)&Xl[(size_t)cr * D_ + c4] =
        (short4v){(short)l[0],(short)l[1],(short)l[2],(short)l[3]};
}

// ---------------------------------------------------------------------------
__global__ __launch_bounds__(256)
void tconv_w(const float* __restrict__ W, unsigned short* __restrict__ Th,
             unsigned short* __restrict__ Tl, int K, int N)
{
    __shared__ float T[64][65];
    const int tid = threadIdx.x;
    const int k0 = blockIdx.x * 64, n0 = blockIdx.y * 64;
    #pragma unroll
    for (int p = 0; p < 4; ++p) {
        const int f = p * 256 + tid;
        const int r = f >> 4, c4 = (f & 15) << 2;
        const float4 v = *(const float4*)&W[(size_t)(k0 + r) * N + n0 + c4];
        T[r][c4] = v.x; T[r][c4 + 1] = v.y; T[r][c4 + 2] = v.z; T[r][c4 + 3] = v.w;
    }
    __syncthreads();
    #pragma unroll
    for (int p = 0; p < 4; ++p) {
        const int f = p * 256 + tid;
        const int r = f >> 4, c4 = (f & 15) << 2;
        unsigned short h[4], l[4];
        #pragma unroll
        for (int i = 0; i < 4; ++i) split2(T[c4 + i][r], h[i], l[i]);
        *(short4v*)&Th[(size_t)(n0 + r) * K + k0 + c4] =
            (short4v){(short)h[0],(short)h[1],(short)h[2],(short)h[3]};
        *(short4v*)&Tl[(size_t)(n0 + r) * K + k0 + c4] =
            (short4v){(short)l[0],(short)l[1],(short)l[2],(short)l[3]};
    }
}

__global__ __launch_bounds__(256)
void tconv_qkv(const float* __restrict__ W0, const float* __restrict__ W1,
               const float* __restrict__ W2, unsigned short* __restrict__ Th,
               unsigned short* __restrict__ Tl)
{
    __shared__ float T[64][65];
    const int z = blockIdx.z;
    const float* W = (z == 0) ? W0 : (z == 1) ? W1 : W2;
    unsigned short* th = Th + ((size_t)z << 20);
    unsigned short* tl = Tl + ((size_t)z << 20);
    const int tid = threadIdx.x;
    const int k0 = blockIdx.x * 64, n0 = blockIdx.y * 64;
    #pragma unroll
    for (int p = 0; p < 4; ++p) {
        const int f = p * 256 + tid;
        const int r = f >> 4, c4 = (f & 15) << 2;
        const float4 v = *(const float4*)&W[(size_t)(k0 + r) * D_ + n0 + c4];
        T[r][c4] = v.x; T[r][c4 + 1] = v.y; T[r][c4 + 2] = v.z; T[r][c4 + 3] = v.w;
    }
    __syncthreads();
    #pragma unroll
    for (int p = 0; p < 4; ++p) {
        const int f = p * 256 + tid;
        const int r = f >> 4, c4 = (f & 15) << 2;
        unsigned short h[4], l[4];
        #pragma unroll
        for (int i = 0; i < 4; ++i) split2(T[c4 + i][r], h[i], l[i]);
        *(short4v*)&th[(size_t)(n0 + r) * D_ + k0 + c4] =
            (short4v){(short)h[0],(short)h[1],(short)h[2],(short)h[3]};
        *(short4v*)&tl[(size_t)(n0 + r) * D_ + k0 + c4] =
            (short4v){(short)l[0],(short)l[1],(short)l[2],(short)l[3]};
    }
}

// ---------------------------------------------------------------------------
// QKV GEMM, BM=64 BN=64 (the measured-faster gemm_out64 geometry: 1536
// active blocks ~ 4/CU resident vs BM128's 3/CU). 4 waves, wave tile 32x32
// (acc 2x2), BK=64 1-phase, 0 bank conflicts. Grid (n, m): XCD = n%8.
// Q cols: 3-term split. K/V cols: 2-term (A-lo neither staged nor used).
// Per-element K-accumulation order identical to round 16 -> bit-identical.
// ---------------------------------------------------------------------------
__global__ __launch_bounds__(256, 4)
void gemm_qkv(const unsigned short* __restrict__ Ah, const unsigned short* __restrict__ Al,
              const unsigned short* __restrict__ Bh, const unsigned short* __restrict__ Bl,
              const float* __restrict__ bq, const float* __restrict__ bk,
              const float* __restrict__ bv,
              unsigned short* __restrict__ Oqh, unsigned short* __restrict__ Oql,
              unsigned short* __restrict__ Okh, unsigned short* __restrict__ Ovt,
              const int* __restrict__ nv)
{
    const int n0 = blockIdx.x * 64, m0 = blockIdx.y * 64;
    const int bb = m0 >> 11;
    const int nvb = nv[bb];
    if ((m0 & 2047) >= nvb) return;

    __shared__ unsigned short As_h[64 * 64], As_l[64 * 64];
    __shared__ unsigned short Bs_h[64 * 64], Bs_l[64 * 64];

    const int tid = threadIdx.x;
    const int lane = tid & 63, w = tid >> 6;
    const int wm = w >> 1, wn = w & 1;          // 2x2 wave grid, 32x32 each
    const int l15 = lane & 15, l4 = lane >> 4;
    const int lr = lane >> 3, lc = lane & 7;
    const int idx = n0 >> 10;                   // 0=Q 1=K 2=V

    f32x4 acc[2][2];
    #pragma unroll
    for (int i = 0; i < 2; ++i)
        #pragma unroll
        for (int j = 0; j < 2; ++j) acc[i][j] = (f32x4){0.f, 0.f, 0.f, 0.f};

    for (int kt = 0; kt < D_; kt += 64) {
        __syncthreads();
        #pragma unroll
        for (int t = 0; t < 2; ++t) {           // A & B: 64 rows, wave covers 16
            const int row = w * 16 + t * 8 + lr;
            const int kc = lc ^ (row & 7);
            const size_t ga = (size_t)(m0 + row) * D_ + kt + kc * 8;
            gl_lds16(&Ah[ga], &As_h[(w * 16 + t * 8) * 64]);
            if (idx == 0)                        // A-lo only needed for Q
                gl_lds16(&Al[ga], &As_l[(w * 16 + t * 8) * 64]);
            const size_t gb = (size_t)(n0 + row) * D_ + kt + kc * 8;
            gl_lds16(&Bh[gb], &Bs_h[(w * 16 + t * 8) * 64]);
            gl_lds16(&Bl[gb], &Bs_l[(w * 16 + t * 8) * 64]);
        }
        __syncthreads();

        #pragma unroll
        for (int kk = 0; kk < 2; ++kk) {
            bf16x8 ah[2], bh2[2], bl2[2];
            #pragma unroll
            for (int i = 0; i < 2; ++i) {
                const int row = wm * 32 + i * 16 + l15;
                const int off = row * 64 + (((kk * 4 + l4) ^ (row & 7)) << 3);
                ah[i] = *(const bf16x8*)&As_h[off];
            }
            #pragma unroll
            for (int j = 0; j < 2; ++j) {
                const int row = wn * 32 + j * 16 + l15;
                const int off = row * 64 + (((kk * 4 + l4) ^ (row & 7)) << 3);
                bh2[j] = *(const bf16x8*)&Bs_h[off];
                bl2[j] = *(const bf16x8*)&Bs_l[off];
            }
            #pragma unroll
            for (int i = 0; i < 2; ++i)
                #pragma unroll
                for (int j = 0; j < 2; ++j) {
                    acc[i][j] = MFMA(ah[i], bh2[j], acc[i][j]);
                    acc[i][j] = MFMA(ah[i], bl2[j], acc[i][j]);
                }
            if (idx == 0) {   // Q: 3rd term with A-lo
                #pragma unroll
                for (int i = 0; i < 2; ++i) {
                    const int row = wm * 32 + i * 16 + l15;
                    const int off = row * 64 + (((kk * 4 + l4) ^ (row & 7)) << 3);
                    const bf16x8 al = *(const bf16x8*)&As_l[off];
                    #pragma unroll
                    for (int j = 0; j < 2; ++j)
                        acc[i][j] = MFMA(al, bh2[j], acc[i][j]);
                }
            }
        }
    }

    const float* bp = (idx == 0) ? bq : (idx == 1) ? bk : bv;
    #pragma unroll
    for (int i = 0; i < 2; ++i) {
        const int m = m0 + wm * 32 + i * 16 + l4 * 4;
        const int jm = m & 2047;
        #pragma unroll
        for (int j = 0; j < 2; ++j) {
            const int nG = n0 + wn * 32 + j * 16 + l15;
            const int c = nG & 1023;
            const float bvv = bp[c];
            const int hh = c >> 6, dd = c & 63;
            if (idx == 0) {
                const size_t base = ((size_t)(bb * H_ + hh) * S_ + jm) * 64 + dd;
                #pragma unroll
                for (int r = 0; r < 4; ++r)
                    if (jm + r < nvb) {
                        unsigned short vh, vl;
                        split2(acc[i][j][r] + bvv, vh, vl);
                        Oqh[base + (size_t)r * 64] = vh;
                        Oql[base + (size_t)r * 64] = vl;
                    }
            } else if (idx == 1) {
                const size_t base = ((size_t)(bb * H_ + hh) * S_ + jm) * 64 + dd;
                #pragma unroll
                for (int r = 0; r < 4; ++r)
                    if (jm + r < nvb)
                        Okh[base + (size_t)r * 64] = bf16_rne(acc[i][j][r] + bvv);
            } else {
                unsigned short pv[4];
                #pragma unroll
                for (int r = 0; r < 4; ++r) pv[r] = bf16_rne(acc[i][j][r] + bvv);
                const size_t vb = ((size_t)(bb * H_ + hh) * 64 + dd) * (size_t)S_ + jm;
                if (jm + 3 < nvb) {
                    *(short4v*)&Ovt[vb] =
                        (short4v){(short)pv[0],(short)pv[1],(short)pv[2],(short)pv[3]};
                } else {
                    #pragma unroll
                    for (int r = 0; r < 4; ++r)
                        if (jm + r < nvb) Ovt[vb + r] = pv[r];
                }
            }
        }
    }
}

// ---------------------------------------------------------------------------
// Output GEMM, 64x64 tile, 4 waves, wave 32x32, 3-term, BK=64 1-phase.
// Scatter via opos.
// ---------------------------------------------------------------------------
__global__ __launch_bounds__(256, 4)
void gemm_out64(const unsigned short* __restrict__ Ah, const unsigned short* __restrict__ Al,
                const unsigned short* __restrict__ Bh, const unsigned short* __restrict__ Bl,
                const float* __restrict__ bias, float* __restrict__ Cf,
                const int* __restrict__ nv, const int* __restrict__ opos)
{
    const int n0 = blockIdx.x * 64, m0 = blockIdx.y * 64;
    const int bb = m0 >> 11;
    const int nvb = nv[bb];
    if ((m0 & 2047) >= nvb) return;

    __shared__ unsigned short As_h[64 * 64], As_l[64 * 64];
    __shared__ unsigned short Bs_h[64 * 64], Bs_l[64 * 64];

    const int tid = threadIdx.x;
    const int lane = tid & 63, w = tid >> 6;
    const int wm = w >> 1, wn = w & 1;                // 2x2 wave grid, 32x32 each
    const int l15 = lane & 15, l4 = lane >> 4;
    const int lr = lane >> 3, lc = lane & 7;

    f32x4 acc[2][2];
    #pragma unroll
    for (int i = 0; i < 2; ++i)
        #pragma unroll
        for (int j = 0; j < 2; ++j) acc[i][j] = (f32x4){0.f, 0.f, 0.f, 0.f};

    for (int kt = 0; kt < D_; kt += 64) {
        __syncthreads();
        #pragma unroll
        for (int t = 0; t < 2; ++t) {
            const int row = w * 16 + t * 8 + lr;
            const int kc = lc ^ (row & 7);
            const size_t ga = (size_t)(m0 + row) * D_ + kt + kc * 8;
            gl_lds16(&Ah[ga], &As_h[(w * 16 + t * 8) * 64]);
            gl_lds16(&Al[ga], &As_l[(w * 16 + t * 8) * 64]);
            const size_t gb = (size_t)(n0 + row) * D_ + kt + kc * 8;
            gl_lds16(&Bh[gb], &Bs_h[(w * 16 + t * 8) * 64]);
            gl_lds16(&Bl[gb], &Bs_l[(w * 16 + t * 8) * 64]);
        }
        __syncthreads();

        #pragma unroll
        for (int kk = 0; kk < 2; ++kk) {
            bf16x8 ah[2], al[2], bh2[2], bl2[2];
            #pragma unroll
            for (int i = 0; i < 2; ++i) {
                const int row = wm * 32 + i * 16 + l15;
                const int off = row * 64 + (((kk * 4 + l4) ^ (row & 7)) << 3);
                ah[i] = *(const bf16x8*)&As_h[off];
                al[i] = *(const bf16x8*)&As_l[off];
            }
            #pragma unroll
            for (int j = 0; j < 2; ++j) {
                const int row = wn * 32 + j * 16 + l15;
                const int off = row * 64 + (((kk * 4 + l4) ^ (row & 7)) << 3);
                bh2[j] = *(const bf16x8*)&Bs_h[off];
                bl2[j] = *(const bf16x8*)&Bs_l[off];
            }
            #pragma unroll
            for (int i = 0; i < 2; ++i)
                #pragma unroll
                for (int j = 0; j < 2; ++j) {
                    acc[i][j] = MFMA(ah[i], bh2[j], acc[i][j]);
                    acc[i][j] = MFMA(ah[i], bl2[j], acc[i][j]);
                    acc[i][j] = MFMA(al[i], bh2[j], acc[i][j]);
                }
        }
    }

    const int* op = opos + bb * 2048;
    #pragma unroll
    for (int i = 0; i < 2; ++i) {
        const int m = m0 + wm * 32 + i * 16 + l4 * 4;
        #pragma unroll
        for (int j = 0; j < 2; ++j) {
            const int n = n0 + wn * 32 + j * 16 + l15;
            const float bvv = bias[n];
            #pragma unroll
            for (int r = 0; r < 4; ++r) {
                const int jr = (m & 2047) + r;
                if (jr < nvb)
                    Cf[((size_t)bb * 2048 + op[jr]) * OUT_ + n] = acc[i][j][r] + bvv;
            }
        }
    }
}

// ---------------------------------------------------------------------------
// Flash attention on COMPACTED q/k. QBLK=64: 4 waves x 16 q-rows (256 thr),
// ~512 active blocks (2/CU, 4 waves/SIMD). 2-phase dbuf staging.
// ---------------------------------------------------------------------------
__global__ __launch_bounds__(256, 3)
void attn_mfma(const unsigned short* __restrict__ Qh, const unsigned short* __restrict__ Ql,
               const unsigned short* __restrict__ Kh, const unsigned short* __restrict__ Vt,
               const int* __restrict__ nv,
               unsigned short* __restrict__ Mh, unsigned short* __restrict__ Ml)
{
    const int bh = blockIdx.x, b = bh >> 4;
    const int nvb = nv[b];
    const int q0 = blockIdx.y * 64;
    if (q0 >= nvb) return;

    __shared__ unsigned short Ks[2][64 * 64];
    __shared__ unsigned short Vts[2][64 * 64];
    __shared__ unsigned short Psb[64 * 72];

    const float SC2  = 0.125f * 1.4426950408889634f;
    const float THR2 = 11.5415603f;
    const float MINIT = -1e5f;
    const float NEGB  = -1e30f;

    const int tid = threadIdx.x;
    const int lane = tid & 63, w = tid >> 6;     // w = 0..3
    const int l15 = lane & 15, l4 = lane >> 4;
    const int qw = q0 + w * 16;

    const int sr8 = lane >> 3, sc7 = lane & 7;

    bf16x8 qh[2], ql[2];
    {
        const int qr = min(qw + l15, nvb - 1);
        const size_t qbase = ((size_t)bh * S_ + qr) * 64;
        #pragma unroll
        for (int kk = 0; kk < 2; ++kk) {
            qh[kk] = *(const bf16x8*)&Qh[qbase + kk * 32 + l4 * 8];
            ql[kk] = *(const bf16x8*)&Ql[qbase + kk * 32 + l4 * 8];
        }
    }

    float m2[4], lp[4];
    f32x4 O[4];
    #pragma unroll
    for (int r = 0; r < 4; ++r) { m2[r] = MINIT; lp[r] = 0.f; }
    #pragma unroll
    for (int df = 0; df < 4; ++df) O[df] = (f32x4){0.f, 0.f, 0.f, 0.f};

    const int NT = (nvb + 63) >> 6;

#define STAGE(KT, SEL)                                                          \
    do {                                                                        \
        _Pragma("unroll")                                                       \
        for (int t = 0; t < 2; ++t) {                                           \
            const int row = w * 16 + t * 8 + sr8;                               \
            const int kc = sc7 ^ (row & 7);                                     \
            gl_lds16(&Kh[((size_t)bh * S_ + (KT) + row) * 64 + kc * 8],         \
                     &Ks[SEL][(w * 16 + t * 8) * 64]);                          \
            gl_lds16(&Vt[((size_t)bh * 64 + row) * (size_t)S_ + (KT) + kc * 8], \
                     &Vts[SEL][(w * 16 + t * 8) * 64]);                         \
        }                                                                       \
    } while (0)

    STAGE(0, 0);
    __syncthreads();

    int cur = 0;
    for (int ti = 0; ti < NT; ++ti, cur ^= 1) {
        const int kt = ti * 64;
        if (ti + 1 < NT) STAGE((ti + 1) * 64, cur ^ 1);

        f32x4 s[4];
        #pragma unroll
        for (int nf = 0; nf < 4; ++nf) s[nf] = (f32x4){0.f, 0.f, 0.f, 0.f};
        #pragma unroll
        for (int nf = 0; nf < 4; ++nf) {
            const int krow = nf * 16 + l15;
            #pragma unroll
            for (int kk = 0; kk < 2; ++kk) {
                const int off = krow * 64 + (((kk * 4 + l4) ^ (krow & 7)) << 3);
                const bf16x8 kh8 = *(const bf16x8*)&Ks[cur][off];
                s[nf] = MFMA(qh[kk], kh8, s[nf]);
                s[nf] = MFMA(ql[kk], kh8, s[nf]);
            }
        }

        float addk[4];
        #pragma unroll
        for (int nf = 0; nf < 4; ++nf)
            addk[nf] = (kt + nf * 16 + l15 < nvb) ? 0.f : NEGB;

        float lm[4];
        bool need = false;
        #pragma unroll
        for (int r = 0; r < 4; ++r) {
            float v0 = fmaf(s[0][r], SC2, addk[0]);
            float v1 = fmaf(s[1][r], SC2, addk[1]);
            float v2 = fmaf(s[2][r], SC2, addk[2]);
            float v3 = fmaf(s[3][r], SC2, addk[3]);
            s[0][r] = v0; s[1][r] = v1; s[2][r] = v2; s[3][r] = v3;
            const float rm = fmaxf(fmaxf(v0, v1), fmaxf(v2, v3));
            lm[r] = rm;
            need |= (rm > m2[r] + THR2);
        }

        if (__any(need)) {
            #pragma unroll
            for (int r = 0; r < 4; ++r) {
                float rm = lm[r];
                rm = fmaxf(rm, __shfl_xor(rm, 1));
                rm = fmaxf(rm, __shfl_xor(rm, 2));
                rm = fmaxf(rm, __shfl_xor(rm, 4));
                rm = fmaxf(rm, __shfl_xor(rm, 8));
                const float mnew = fmaxf(m2[r], rm);
                const float sc = fast_exp2(m2[r] - mnew);
                lp[r] *= sc;
                m2[r] = mnew;
                #pragma unroll
                for (int df = 0; df < 4; ++df) O[df][r] *= sc;
            }
        }

        #pragma unroll
        for (int r = 0; r < 4; ++r) {
            const float mm = m2[r];
            const int qq = w * 16 + l4 * 4 + r;
            const int qbase = qq * 72;
            const int qswz = qq & 7;
            float rs = 0.f;
            #pragma unroll
            for (int nf = 0; nf < 4; ++nf) {
                const float pv = fast_exp2(s[nf][r] - mm);
                rs += pv;
                const int key = nf * 16 + l15;
                Psb[qbase + (((key >> 3) ^ qswz) << 3) + (key & 7)] = bf16_rne(pv);
            }
            lp[r] += rs;
        }

        #pragma unroll
        for (int kk = 0; kk < 2; ++kk) {
            const int qq = w * 16 + l15;
            const bf16x8 ph = *(const bf16x8*)
                &Psb[qq * 72 + ((((kk * 4) + l4) ^ (qq & 7)) << 3)];
            #pragma unroll
            for (int df = 0; df < 4; ++df) {
                const int vrow = df * 16 + l15;
                const int off = vrow * 64 + (((kk * 4 + l4) ^ (vrow & 7)) << 3);
                const bf16x8 vb = *(const bf16x8*)&Vts[cur][off];
                O[df] = MFMA(ph, vb, O[df]);
            }
        }

        __syncthreads();
    }
#undef STAGE

    #pragma unroll
    for (int r = 0; r < 4; ++r) {
        float t = lp[r];
        t += __shfl_xor(t, 1);
        t += __shfl_xor(t, 2);
        t += __shfl_xor(t, 4);
        t += __shfl_xor(t, 8);
        const int j = qw + l4 * 4 + r;
        if (j < nvb) {
            const float inv = (t > 0.f) ? 1.f / t : 0.f;
            const size_t base = ((size_t)b * S_ + j) * D_ + (bh & 15) * DH_;
            #pragma unroll
            for (int df = 0; df < 4; ++df) {
                unsigned short vh, vl;
                split2(O[df][r] * inv, vh, vl);
                Mh[base + df * 16 + l15] = vh;
                Ml[base + df * 16 + l15] = vl;
            }
        }
    }
}

// ---------------------------------------------------------------------------
extern "C" void kernel_launch(void* const* d_in, const int* in_sizes, int n_in,
                              void* d_out, int out_size, void* d_ws, size_t ws_size,
                              hipStream_t stream)
{
    const float* x    = (const float*)d_in[0];
    const float* mask = (const float*)d_in[1];
    const float* Wq   = (const float*)d_in[2];
    const float* bq   = (const float*)d_in[3];
    const float* Wk   = (const float*)d_in[4];
    const float* bk   = (const float*)d_in[5];
    const float* Wv   = (const float*)d_in[6];
    const float* bv   = (const float*)d_in[7];
    const float* Wo   = (const float*)d_in[8];
    const float* bo   = (const float*)d_in[9];
    float* out = (float*)d_out;

    char* ws = (char*)d_ws;
    unsigned short* xh = (unsigned short*)(ws);                      // 8MB (later mh)
    unsigned short* xl = (unsigned short*)(ws + ((size_t) 8 << 20)); // 8MB (later ml)
    unsigned short* qh = (unsigned short*)(ws + ((size_t)16 << 20));
    unsigned short* qll= (unsigned short*)(ws + ((size_t)24 << 20));
    unsigned short* kh = (unsigned short*)(ws + ((size_t)32 << 20));
    unsigned short* vt = (unsigned short*)(ws + ((size_t)40 << 20)); // V^T [bh][d][s]
    unsigned short* wc_h = (unsigned short*)(ws + ((size_t)48 << 20)); // 6MB
    unsigned short* wc_l = (unsigned short*)(ws + ((size_t)54 << 20)); // 6MB
    unsigned short* wo_h = wc_h;            // reuse after QKV GEMM
    unsigned short* wo_l = (unsigned short*)(ws + ((size_t)50 << 20));
    unsigned short* mh = xh;                // x dead after QKV GEMM
    unsigned short* ml = xl;
    int* cpos = (int*)(ws + ((size_t)60 << 20));          // 16KB
    int* opos = (int*)(ws + ((size_t)60 << 20) + 16384);  // 16KB
    int* nv   = (int*)(ws + ((size_t)60 << 20) + 32768);  // 8B

    const dim3 blk(256);
    scan_mask<<<dim3(B_), blk, 0, stream>>>(mask, cpos, opos, nv);
    split_x_c<<<dim3(M_), blk, 0, stream>>>(x, mask, cpos, xh, xl, out, bo);
    tconv_qkv<<<dim3(16, 16, 3), blk, 0, stream>>>(Wq, Wk, Wv, wc_h, wc_l);

    // grid = (n-blocks, m-blocks): XCD = n%8 -> B-slices L2-resident
    gemm_qkv<<<dim3(3 * D_ / 64, M_ / 64), blk, 0, stream>>>(
        xh, xl, wc_h, wc_l, bq, bk, bv, qh, qll, kh, vt, nv);

    tconv_w<<<dim3(16, 16), blk, 0, stream>>>(Wo, wo_h, wo_l, D_, OUT_);

    attn_mfma<<<dim3(B_ * H_, S_ / 64), blk, 0, stream>>>(
        qh, qll, kh, vt, nv, mh, ml);

    gemm_out64<<<dim3(OUT_ / 64, M_ / 64), blk, 0, stream>>>(
        mh, ml, wo_h, wo_l, bo, out, nv, opos);
}